// Round 7
// baseline (442.053 us; speedup 1.0000x reference)
//
#include <hip/hip_runtime.h>
#include <hip/hip_bf16.h>

#define S_LEN 2048
#define DMODEL 4096
#define NH 32
#define NKV 8
#define HD 128
#define NQKV 6144
// 1/sqrt(128) * log2(e): scores scaled into log2 domain so v_exp_f32 (=2^x) is exp
#define ATT_SCALE_L2E 0.1275175213528852f

typedef __bf16 bf16x8 __attribute__((ext_vector_type(8)));
typedef float f32x4 __attribute__((ext_vector_type(4)));

// float -> bf16 bits, round-to-nearest-even
__device__ __forceinline__ unsigned short f2b(float f) {
  union { float f; unsigned u; } a; a.f = f;
  unsigned u = a.u;
  return (unsigned short)((u + 0x7FFFu + ((u >> 16) & 1u)) >> 16);
}

__device__ __forceinline__ void gl16(const unsigned short* g, unsigned short* l) {
  __builtin_amdgcn_global_load_lds(
      (const __attribute__((address_space(1))) unsigned int*)g,
      (__attribute__((address_space(3))) unsigned int*)l, 16, 0, 0);
}

// ---------------- x fp32 -> bf16 ----------------
__global__ __launch_bounds__(256) void k_cvt_x(const float* __restrict__ x,
                                               unsigned short* __restrict__ xb) {
  int i = blockIdx.x * 256 + threadIdx.x;
  float4 v = ((const float4*)x)[i];
  ushort4 o;
  o.x = f2b(v.x); o.y = f2b(v.y); o.z = f2b(v.z); o.w = f2b(v.w);
  ((ushort4*)xb)[i] = o;
}

// ------------- W (K,N) fp32 -> Wt (N,K) bf16 -------------
__global__ __launch_bounds__(256) void k_transpose(const float* __restrict__ W,
                                                   unsigned short* __restrict__ Wt,
                                                   int K, int N) {
  __shared__ float tile[64][65];
  int k0 = blockIdx.x * 64, n0 = blockIdx.y * 64;
  int tx = threadIdx.x & 31, ty = threadIdx.x >> 5;
#pragma unroll
  for (int i = 0; i < 8; ++i) {
    int k = ty + i * 8;
    const float* src = W + (size_t)(k0 + k) * N + n0;
    tile[k][tx] = src[tx];
    tile[k][tx + 32] = src[tx + 32];
  }
  __syncthreads();
#pragma unroll
  for (int i = 0; i < 8; ++i) {
    int n = ty + i * 8;
    unsigned short* dst = Wt + (size_t)(n0 + n) * K + k0;
    dst[tx] = f2b(tile[tx][n]);
    dst[tx + 32] = f2b(tile[tx + 32][n]);
  }
}

// ------------- V [S][NKV][HD] bf16 -> V^T [NKV][HD][S] bf16 -------------
__global__ __launch_bounds__(256) void k_vt(const unsigned short* __restrict__ v_bf,
                                            unsigned short* __restrict__ v_t) {
  __shared__ unsigned short tile[64][65];
  int s0 = blockIdx.x * 64, d0 = blockIdx.y * 64, kvh = blockIdx.z;
  int tx = threadIdx.x & 63, ty = threadIdx.x >> 6;
#pragma unroll
  for (int i = 0; i < 16; ++i) {
    int s = ty + i * 4;
    tile[s][tx] = v_bf[((size_t)(s0 + s) * NKV + kvh) * HD + d0 + tx];
  }
  __syncthreads();
#pragma unroll
  for (int i = 0; i < 16; ++i) {
    int d = ty + i * 4;
    v_t[((size_t)kvh * HD + d0 + d) * S_LEN + s0 + tx] = tile[tx][d];
  }
}

// ============ 256 x (FN*64) 2-phase GEMM: C(MxN) fp32 = A(MxK) bf16 * Bt(NxK) bf16 ====
// BM=256, BN=FN*64, BK=64, 512 threads = 8 waves (2Mx4N); per-wave output 128 x FN*16.
// FN=3 -> QKV proj grid 8x32=256; FN=2 -> out proj grid 8x32=256. Exact 1 block/CU.
// LDS: A 2x(2x16KB halves) at [0,64K); B 2x(FN*8KB) at [64K,...).
// G4 swizzle byte ^= ((row&7)<<4) via pre-swizzled gl16 source + swizzled ds_read col.
// Per K-tile: ph1 {read A-h0 + B, stage B(t+1), MFMA}; ph2 {read A-h1, stage A-h0(t+2),
// MFMA}; boundary {stage A-h1(t+2), vmcnt(4), barrier}.
template <int FN>
__global__ __launch_bounds__(512, 2) void k_gemmN(const unsigned short* __restrict__ A,
                                                  const unsigned short* __restrict__ B,
                                                  float* __restrict__ C,
                                                  int M, int N, int K) {
  extern __shared__ __align__(16) unsigned short smem[];
  char* Sc = (char*)smem;
  const int tid = threadIdx.x;
  const int wvid = tid >> 6, l = tid & 63;
  const int wm = wvid >> 2, wn = wvid & 3;
  const int l15 = l & 15, l4 = l >> 4;

  // XCD-bijective swizzle (nwg = 256 at both call sites)
  const int nwg = gridDim.x;
  const int cpx = nwg >> 3;
  const int bid = blockIdx.x;
  const int swz = (bid & 7) * cpx + (bid >> 3);
  const int mtiles = M >> 8;
  const int m0 = (swz % mtiles) * 256;
  const int n0 = (swz / mtiles) * (FN * 64);

  const int NT = K >> 6;

  const int rsw = (l15 & 7) << 4;
  const int a_base = (wm * 64 + l15) * 128;        // + fm*2048 + c{0,1}, within 16KB half
  const int b_base = (wn * FN * 16 + l15) * 128;   // + fn*2048 + c{0,1}
  const int c0 = (l4 * 16) ^ rsw;
  const int c1 = (64 + l4 * 16) ^ rsw;

  // stage-side: dest (row = blk*8 + l>>3, slot = l&7) <- global k8 = (l&7)^(l>>3)
  const int st_row = l >> 3;
  const int st_k8 = (l & 7) ^ st_row;

  auto stA = [&](int tt, int h) {  // 16 KB half: 2 gl16 per thread
    if (tt >= NT) return;
    const unsigned short* g = A + (size_t)(m0 + h * 128) * K + tt * 64 + st_k8 * 8;
    unsigned short* lb = (unsigned short*)(Sc + (tt & 1) * 32768 + h * 16384);
#pragma unroll
    for (int j = 0; j < 2; ++j) {
      int blk = j * 8 + wvid;
      gl16(g + (size_t)(blk * 8 + st_row) * K, lb + blk * 512);
    }
  };
  auto stB = [&](int tt) {  // FN*8 KB tile: FN gl16 per thread
    if (tt >= NT) return;
    const unsigned short* g = B + (size_t)n0 * K + tt * 64 + st_k8 * 8;
    unsigned short* lb = (unsigned short*)(Sc + 65536 + (tt & 1) * (FN * 8192));
#pragma unroll
    for (int j = 0; j < FN; ++j) {
      int blk = j * 8 + wvid;
      gl16(g + (size_t)(blk * 8 + st_row) * K, lb + blk * 512);
    }
  };

  f32x4 acc[2][4][FN] = {};

  // ---- prologue ----
  stA(0, 0); stA(0, 1); stB(0);
  stA(1, 0); stA(1, 1);
  if (NT > 1) asm volatile("s_waitcnt vmcnt(4)" ::: "memory");
  else        asm volatile("s_waitcnt vmcnt(0)" ::: "memory");
  __builtin_amdgcn_s_barrier();

  for (int t = 0; t < NT; ++t) {
    const int b = t & 1;
    const char* Ab = Sc + b * 32768;
    const char* Bb = Sc + 65536 + b * (FN * 8192);
    bf16x8 a[4][2], bb[FN][2];

    // ===== phase 1: A-h0 x B — read A-h0(8) + B(2*FN); stage B(t+1) =====
#pragma unroll
    for (int fm = 0; fm < 4; ++fm) {
      a[fm][0] = *(const bf16x8*)(Ab + a_base + fm * 2048 + c0);
      a[fm][1] = *(const bf16x8*)(Ab + a_base + fm * 2048 + c1);
    }
#pragma unroll
    for (int fn = 0; fn < FN; ++fn) {
      bb[fn][0] = *(const bf16x8*)(Bb + b_base + fn * 2048 + c0);
      bb[fn][1] = *(const bf16x8*)(Bb + b_base + fn * 2048 + c1);
    }
    stB(t + 1);
    __builtin_amdgcn_s_barrier();
    __builtin_amdgcn_s_setprio(1);
#pragma unroll
    for (int fm = 0; fm < 4; ++fm)
#pragma unroll
      for (int fn = 0; fn < FN; ++fn)
#pragma unroll
        for (int ks = 0; ks < 2; ++ks)
          acc[0][fm][fn] = __builtin_amdgcn_mfma_f32_16x16x32_bf16(a[fm][ks], bb[fn][ks], acc[0][fm][fn], 0, 0, 0);
    __builtin_amdgcn_s_setprio(0);
    __builtin_amdgcn_s_barrier();

    // ===== phase 2: A-h1 x B — read A-h1(8); stage A-h0(t+2); B held in regs =====
#pragma unroll
    for (int fm = 0; fm < 4; ++fm) {
      a[fm][0] = *(const bf16x8*)(Ab + 16384 + a_base + fm * 2048 + c0);
      a[fm][1] = *(const bf16x8*)(Ab + 16384 + a_base + fm * 2048 + c1);
    }
    stA(t + 2, 0);
    __builtin_amdgcn_s_barrier();
    __builtin_amdgcn_s_setprio(1);
#pragma unroll
    for (int fm = 0; fm < 4; ++fm)
#pragma unroll
      for (int fn = 0; fn < FN; ++fn)
#pragma unroll
        for (int ks = 0; ks < 2; ++ks)
          acc[1][fm][fn] = __builtin_amdgcn_mfma_f32_16x16x32_bf16(a[fm][ks], bb[fn][ks], acc[1][fm][fn], 0, 0, 0);
    __builtin_amdgcn_s_setprio(0);
    __builtin_amdgcn_s_barrier();

    // ===== boundary: stage A-h1(t+2); counted vmcnt =====
    stA(t + 2, 1);
    if (t + 1 < NT) {
      if (t + 1 == NT - 1) asm volatile("s_waitcnt vmcnt(0)" ::: "memory");
      else                 asm volatile("s_waitcnt vmcnt(4)" ::: "memory");
      __builtin_amdgcn_s_barrier();
    }
  }

  // ---- epilogue: C write ----
#pragma unroll
  for (int h = 0; h < 2; ++h)
#pragma unroll
    for (int fm = 0; fm < 4; ++fm) {
      int row0 = m0 + h * 128 + wm * 64 + fm * 16 + l4 * 4;
#pragma unroll
      for (int fn = 0; fn < FN; ++fn) {
        int col = n0 + wn * FN * 16 + fn * 16 + l15;
#pragma unroll
        for (int r = 0; r < 4; ++r)
          C[(size_t)(row0 + r) * N + col] = acc[h][fm][fn][r];
      }
    }
}

// ------------- RoPE + int8 quantize (stored as bf16 ints) -------------
__global__ __launch_bounds__(256) void k_ropequant(const float* __restrict__ qkv,
                                                   const float* __restrict__ cost,
                                                   const float* __restrict__ sint,
                                                   unsigned short* __restrict__ q_int,
                                                   float* __restrict__ q_ds,
                                                   unsigned short* __restrict__ k_int,
                                                   float* __restrict__ k_ds,
                                                   unsigned short* __restrict__ v_bf) {
  int s = blockIdx.x;
  int wv = threadIdx.x >> 6, l = threadIdx.x & 63;
  int hh = blockIdx.y * 4 + wv;  // 0..47: [0,32) q, [32,40) k, [40,48) v
  const float* row = qkv + (size_t)s * NQKV;
  if (hh < NH + NKV) {
    int off = (hh < NH) ? hh * HD : DMODEL + (hh - NH) * HD;
    float t1 = row[off + l], t2 = row[off + 64 + l];
    float c1 = cost[s * HD + l],      sn1 = sint[s * HD + l];
    float c2 = cost[s * HD + 64 + l], sn2 = sint[s * HD + 64 + l];
    float o1 = t1 * c1 - t2 * sn1;
    float o2 = t2 * c2 + t1 * sn2;
    float amax = fmaxf(fabsf(o1), fabsf(o2));
#pragma unroll
    for (int m = 1; m < 64; m <<= 1) amax = fmaxf(amax, __shfl_xor(amax, m));
    amax = fmaxf(amax, 1e-5f);
    float scale = 127.0f / amax;
    float dscale = amax * (1.0f / 127.0f);
    float v1 = fminf(fmaxf(rintf(o1 * scale), -128.f), 127.f);
    float v2 = fminf(fmaxf(rintf(o2 * scale), -128.f), 127.f);
    if (hh < NH) {
      unsigned short* dst = q_int + ((size_t)s * NH + hh) * HD;
      dst[l] = f2b(v1); dst[l + 64] = f2b(v2);
      if (l == 0) q_ds[(size_t)s * NH + hh] = dscale;
    } else {
      int kh = hh - NH;
      unsigned short* dst = k_int + ((size_t)s * NKV + kh) * HD;
      dst[l] = f2b(v1); dst[l + 64] = f2b(v2);
      if (l == 0) k_ds[(size_t)s * NKV + kh] = dscale;
    }
  } else {
    int vh = hh - (NH + NKV);
    const float* src = row + DMODEL + NKV * HD + vh * HD;
    unsigned short* dst = v_bf + ((size_t)s * NKV + vh) * HD;
    dst[l] = f2b(src[l]);
    dst[l + 64] = f2b(src[l + 64]);
  }
}

// ------------- causal GQA flash attention -------------
// 1024 blocks, one q-tile each, dispatched longest-first (LPT); K double-buffered in LDS
// (async gl16, XOR-swizzled); V read per-fragment from XCD-pinned L2 (no V_lds);
// softmax in log2 domain (v_exp_f32 native); T13 defer-max THR=11 bits.
// LDS 41 KB -> 3 blocks/CU capacity; launch_bounds caps VGPR for 3 waves/SIMD.
__global__ __launch_bounds__(256, 3) void k_attn(const unsigned short* __restrict__ q_int,
                                                 const float* __restrict__ q_ds,
                                                 const unsigned short* __restrict__ k_int,
                                                 const float* __restrict__ k_ds,
                                                 const unsigned short* __restrict__ v_t,
                                                 unsigned short* __restrict__ o_bf) {
  __shared__ __align__(16) unsigned short K_lds[2][8192];
  __shared__ __align__(16) unsigned short P_lds[4][16 * 72];

  const int bid = blockIdx.x;
  const int kvh = bid & 7;                 // kvh == XCD under %8 round-robin
  const int h = kvh * 4 + ((bid >> 3) & 3);
  const int qt = 31 - (bid >> 5);          // longest blocks dispatch first (LPT)
  const int tid = threadIdx.x, wv = tid >> 6, l = tid & 63;
  const int l15 = l & 15, l4 = l >> 4;

  auto stage = [&](int b, int kt) {
    const unsigned short* kB = k_int + (size_t)kt * 64 * (NKV * HD) + kvh * HD;
#pragma unroll
    for (int j = 0; j < 4; ++j) {
      int wi = j * 4 + wv;
      int slot = wi * 64 + l;
      int key = slot >> 4;
      int colb = ((slot & 15) * 16) ^ ((key & 7) << 4);
      gl16(kB + key * (NKV * HD) + (colb >> 1), &K_lds[b][wi * 512]);
    }
  };

  const int qrow_lo = qt * 64 + wv * 16;
  const int crow = qrow_lo + l4 * 4;

  bf16x8 qf[4];
  {
    const unsigned short* qp = q_int + ((size_t)(qrow_lo + l15) * NH + h) * HD + l4 * 8;
#pragma unroll
    for (int kd = 0; kd < 4; ++kd) qf[kd] = *(const bf16x8*)(qp + kd * 32);
  }
  float qsS[4];
#pragma unroll
  for (int r = 0; r < 4; ++r) qsS[r] = ATT_SCALE_L2E * q_ds[(size_t)(crow + r) * NH + h];

  // per-lane V^T base: row d = l15 (+dt*16), key = l4*8 (+kc*32 +kt*64)
  const unsigned short* vrow = v_t + ((size_t)kvh * HD + l15) * S_LEN + l4 * 8;

  float m_run[4], l_run[4];
  f32x4 o_acc[8] = {};
#pragma unroll
  for (int r = 0; r < 4; ++r) { m_run[r] = -3.0e38f; l_run[r] = 0.f; }

  const int nkt = qt + 1;
  stage(0, 0);
  __syncthreads();  // drains vmcnt: tile 0 staged

  for (int kt = 0; kt < nkt; ++kt) {
    const int cur = kt & 1;
    float ksd[4];
#pragma unroll
    for (int nt = 0; nt < 4; ++nt)
      ksd[nt] = k_ds[(size_t)(kt * 64 + nt * 16 + l15) * NKV + kvh];
    if (kt + 1 < nkt) stage(cur ^ 1, kt + 1);  // async prefetch into other buffer

    // ---- QK^T (exact int accumulate in fp32) ----
    f32x4 sacc[4] = {};
#pragma unroll
    for (int nt = 0; nt < 4; ++nt) {
      int key = nt * 16 + l15;
#pragma unroll
      for (int kd = 0; kd < 4; ++kd) {
        int byte = key * 256 + kd * 64 + l4 * 16;
        byte ^= (key & 7) << 4;
        bf16x8 kf = *(const bf16x8*)((const char*)&K_lds[cur][0] + byte);
        sacc[nt] = __builtin_amdgcn_mfma_f32_16x16x32_bf16(qf[kd], kf, sacc[nt], 0, 0, 0);
      }
    }

    // ---- scale (log2 domain) + causal mask + online softmax ----
    float p[4][4];
    float tmax[4] = {-3.0e38f, -3.0e38f, -3.0e38f, -3.0e38f};
#pragma unroll
    for (int nt = 0; nt < 4; ++nt) {
      int keyg = kt * 64 + nt * 16 + l15;
#pragma unroll
      for (int r = 0; r < 4; ++r) {
        float sc = sacc[nt][r] * (qsS[r] * ksd[nt]);
        sc = (keyg <= crow + r) ? sc : -3.0e38f;
        p[nt][r] = sc;
        tmax[r] = fmaxf(tmax[r], sc);
      }
    }
#pragma unroll
    for (int m = 1; m < 16; m <<= 1)
#pragma unroll
      for (int r = 0; r < 4; ++r) tmax[r] = fmaxf(tmax[r], __shfl_xor(tmax[r], m));

    // T13 defer-max: only rescale when max grew by > 11 bits (2^11 headroom in P)
    bool needrs = false;
    float nm[4];
#pragma unroll
    for (int r = 0; r < 4; ++r) {
      nm[r] = fmaxf(m_run[r], tmax[r]);
      needrs |= (tmax[r] > m_run[r] + 11.0f);
    }
    if (__ballot(needrs)) {
#pragma unroll
      for (int r = 0; r < 4; ++r) {
        float corr = __builtin_amdgcn_exp2f(m_run[r] - nm[r]);
        m_run[r] = nm[r];
        l_run[r] *= corr;
#pragma unroll
        for (int dt = 0; dt < 8; ++dt) o_acc[dt][r] *= corr;
      }
    }

    float psum[4] = {0.f, 0.f, 0.f, 0.f};
#pragma unroll
    for (int nt = 0; nt < 4; ++nt)
#pragma unroll
      for (int r = 0; r < 4; ++r) {
        float e = __builtin_amdgcn_exp2f(p[nt][r] - m_run[r]);
        p[nt][r] = e;
        psum[r] += e;
      }
#pragma unroll
    for (int m = 1; m < 16; m <<= 1)
#pragma unroll
      for (int r = 0; r < 4; ++r) psum[r] += __shfl_xor(psum[r], m);
#pragma unroll
    for (int r = 0; r < 4; ++r) l_run[r] += psum[r];

    // ---- V prefetch (dt=0,1) from L2 — overlaps the P LDS round-trip ----
    const unsigned short* vt0 = vrow + kt * 64;
    bf16x8 vv[2][2];
    vv[0][0] = *(const bf16x8*)(vt0);
    vv[0][1] = *(const bf16x8*)(vt0 + 32);
    vv[1][0] = *(const bf16x8*)(vt0 + 16 * S_LEN);
    vv[1][1] = *(const bf16x8*)(vt0 + 16 * S_LEN + 32);

    // ---- P -> per-wave LDS ----
#pragma unroll
    for (int nt = 0; nt < 4; ++nt)
#pragma unroll
      for (int r = 0; r < 4; ++r)
        P_lds[wv][(l4 * 4 + r) * 72 + nt * 16 + l15] = f2b(p[nt][r]);

    bf16x8 pa[2];
#pragma unroll
    for (int kc = 0; kc < 2; ++kc)
      pa[kc] = *(const bf16x8*)((const char*)&P_lds[wv][0] + l15 * 144 + kc * 64 + l4 * 16);

    // ---- PV: O += P(16x64) * V(64x128), V from L2, 2-deep rotated pipeline ----
#pragma unroll
    for (int dt = 0; dt < 8; ++dt) {
      bf16x8 x0 = vv[dt & 1][0], x1 = vv[dt & 1][1];
      if (dt < 6) {
        vv[dt & 1][0] = *(const bf16x8*)(vt0 + (dt + 2) * 16 * S_LEN);
        vv[dt & 1][1] = *(const bf16x8*)(vt0 + (dt + 2) * 16 * S_LEN + 32);
      }
      o_acc[dt] = __builtin_amdgcn_mfma_f32_16x16x32_bf16(pa[0], x0, o_acc[dt], 0, 0, 0);
      o_acc[dt] = __builtin_amdgcn_mfma_f32_16x16x32_bf16(pa[1], x1, o_acc[dt], 0, 0, 0);
    }
    __syncthreads();  // next K tile staged; orders K buffer reuse
  }

  float inv_l[4];
#pragma unroll
  for (int r = 0; r < 4; ++r) inv_l[r] = 1.0f / l_run[r];
#pragma unroll
  for (int dt = 0; dt < 8; ++dt)
#pragma unroll
    for (int r = 0; r < 4; ++r)
      o_bf[(size_t)(crow + r) * (NH * HD) + h * HD + dt * 16 + l15] = f2b(o_acc[dt][r] * inv_l[r]);
}

extern "C" void kernel_launch(void* const* d_in, const int* in_sizes, int n_in,
                              void* d_out, int out_size, void* d_ws, size_t ws_size,
                              hipStream_t stream) {
  const float* x    = (const float*)d_in[0];
  const float* Wq   = (const float*)d_in[1];
  const float* Wk   = (const float*)d_in[2];
  const float* Wv   = (const float*)d_in[3];
  const float* Wo   = (const float*)d_in[4];
  const float* cost = (const float*)d_in[5];
  const float* sint = (const float*)d_in[6];
  float* out = (float*)d_out;
  char* ws = (char*)d_ws;

  unsigned short* xb     = (unsigned short*)(ws);                 // 16 MB (dead after gemm1)
  unsigned short* wqkv_t = (unsigned short*)(ws + 16777216);      // 48 MB (dead after gemm1)
  unsigned short* wo_t   = (unsigned short*)(ws + 67108864);      // 32 MB (4096x4096)
  float*          qkv    = (float*)(ws + 100663296);              // 48 MB (dead after ropequant)
  unsigned short* q_int  = (unsigned short*)(ws + 150994944);     // 16 MB
  unsigned short* k_int  = (unsigned short*)(ws + 167772160);     // 4 MB
  unsigned short* v_bf   = (unsigned short*)(ws + 171966464);     // 4 MB
  float*          q_ds   = (float*)(ws + 176160768);              // 256 KB
  float*          k_ds   = (float*)(ws + 176422912);              // 64 KB
  unsigned short* o_bf   = (unsigned short*)(ws + 176488448);     // 16 MB
  unsigned short* v_t    = (unsigned short*)(ws);                 // 4 MB, aliases dead xb

  hipFuncSetAttribute((const void*)k_gemmN<3>,
                      hipFuncAttributeMaxDynamicSharedMemorySize, 114688);
  hipFuncSetAttribute((const void*)k_gemmN<2>,
                      hipFuncAttributeMaxDynamicSharedMemorySize, 98304);

  k_cvt_x<<<(S_LEN * DMODEL / 4) / 256, 256, 0, stream>>>(x, xb);
  k_transpose<<<dim3(64, 64), 256, 0, stream>>>(Wq, wqkv_t, 4096, 4096);
  k_transpose<<<dim3(64, 16), 256, 0, stream>>>(Wk, wqkv_t + (size_t)4096 * 4096, 4096, 1024);
  k_transpose<<<dim3(64, 16), 256, 0, stream>>>(Wv, wqkv_t + (size_t)5120 * 4096, 4096, 1024);
  k_transpose<<<dim3(64, 64), 256, 0, stream>>>(Wo, wo_t, 4096, 4096);
  // QKV proj: 256x192 tiles -> 8 x 32 = 256 blocks = exact full-CU fill
  k_gemmN<3><<<dim3(256), 512, 114688, stream>>>(xb, wqkv_t, qkv, 2048, 6144, 4096);
  k_ropequant<<<dim3(2048, 12), 256, 0, stream>>>(qkv, cost, sint, q_int, q_ds, k_int, k_ds, v_bf);
  k_vt<<<dim3(32, 2, 8), 256, 0, stream>>>(v_bf, v_t);
  k_attn<<<dim3(1024), 256, 0, stream>>>(q_int, q_ds, k_int, k_ds, v_t, o_bf);
  // out proj: 256x128 tiles -> 8 x 32 = 256 blocks = exact full-CU fill (no split-K)
  k_gemmN<2><<<dim3(256), 512, 98304, stream>>>(o_bf, wo_t, out, 2048, 4096, 4096);
}

// Round 8
// 340.733 us; speedup vs baseline: 1.2974x; 1.2974x over previous
//
#include <hip/hip_runtime.h>
#include <hip/hip_bf16.h>

#define S_LEN 2048
#define DMODEL 4096
#define NH 32
#define NKV 8
#define HD 128
#define NQKV 6144
// 1/sqrt(128) * log2(e): scores in log2 domain so v_exp_f32 (=2^x) is the exp
#define ATT_SCALE_L2E 0.1275175213528852f

typedef __bf16 bf16x8 __attribute__((ext_vector_type(8)));
typedef __bf16 bf16x4 __attribute__((ext_vector_type(4)));
typedef float f32x4 __attribute__((ext_vector_type(4)));

// float -> bf16 bits, round-to-nearest-even (bit manual; proven)
__device__ __forceinline__ unsigned short f2b(float f) {
  union { float f; unsigned u; } a; a.f = f;
  unsigned u = a.u;
  return (unsigned short)((u + 0x7FFFu + ((u >> 16) & 1u)) >> 16);
}

__device__ __forceinline__ void gl16(const unsigned short* g, unsigned short* l) {
  __builtin_amdgcn_global_load_lds(
      (const __attribute__((address_space(1))) unsigned int*)g,
      (__attribute__((address_space(3))) unsigned int*)l, 16, 0, 0);
}

// ---------------- x fp32 -> bf16 ----------------
__global__ __launch_bounds__(256) void k_cvt_x(const float* __restrict__ x,
                                               unsigned short* __restrict__ xb) {
  int i = blockIdx.x * 256 + threadIdx.x;
  float4 v = ((const float4*)x)[i];
  ushort4 o;
  o.x = f2b(v.x); o.y = f2b(v.y); o.z = f2b(v.z); o.w = f2b(v.w);
  ((ushort4*)xb)[i] = o;
}

// ------------- W (K,N) fp32 -> Wt (N,K) bf16, ushort4 stores -------------
__global__ __launch_bounds__(256) void k_transpose(const float* __restrict__ W,
                                                   unsigned short* __restrict__ Wt,
                                                   int K, int N) {
  __shared__ float tile[64][65];
  int k0 = blockIdx.x * 64, n0 = blockIdx.y * 64;
  int tx = threadIdx.x & 31, ty = threadIdx.x >> 5;
#pragma unroll
  for (int i = 0; i < 8; ++i) {
    int k = ty + i * 8;
    const float* src = W + (size_t)(k0 + k) * N + n0;
    tile[k][tx] = src[tx];
    tile[k][tx + 32] = src[tx + 32];
  }
  __syncthreads();
  // write phase: unit = (n, kq); each thread stores ushort4 (4 consecutive k)
  int kq = threadIdx.x & 15, nb = threadIdx.x >> 4;
#pragma unroll
  for (int i = 0; i < 4; ++i) {
    int n = nb + i * 16;
    ushort4 o;
    o.x = f2b(tile[kq * 4 + 0][n]);
    o.y = f2b(tile[kq * 4 + 1][n]);
    o.z = f2b(tile[kq * 4 + 2][n]);
    o.w = f2b(tile[kq * 4 + 3][n]);
    *(ushort4*)&Wt[(size_t)(n0 + n) * K + k0 + kq * 4] = o;
  }
}

// ------------- V [S][NKV][HD] bf16 -> V^T [NKV][HD][S] bf16 -------------
__global__ __launch_bounds__(256) void k_vt(const unsigned short* __restrict__ v_bf,
                                            unsigned short* __restrict__ v_t) {
  __shared__ unsigned short tile[64][65];
  int s0 = blockIdx.x * 64, d0 = blockIdx.y * 64, kvh = blockIdx.z;
  int tx = threadIdx.x & 63, ty = threadIdx.x >> 6;
#pragma unroll
  for (int i = 0; i < 16; ++i) {
    int s = ty + i * 4;
    tile[s][tx] = v_bf[((size_t)(s0 + s) * NKV + kvh) * HD + d0 + tx];
  }
  __syncthreads();
#pragma unroll
  for (int i = 0; i < 16; ++i) {
    int d = ty + i * 4;
    v_t[((size_t)kvh * HD + d0 + d) * S_LEN + s0 + tx] = tile[tx][d];
  }
}

// ============ 256 x (FN*64) 2-phase GEMM: C(MxN) fp32 = A(MxK) bf16 * Bt(NxK) bf16 ====
// (unchanged from round 7 — both instantiations verified)
template <int FN>
__global__ __launch_bounds__(512, 2) void k_gemmN(const unsigned short* __restrict__ A,
                                                  const unsigned short* __restrict__ B,
                                                  float* __restrict__ C,
                                                  int M, int N, int K) {
  extern __shared__ __align__(16) unsigned short smem[];
  char* Sc = (char*)smem;
  const int tid = threadIdx.x;
  const int wvid = tid >> 6, l = tid & 63;
  const int wm = wvid >> 2, wn = wvid & 3;
  const int l15 = l & 15, l4 = l >> 4;

  const int nwg = gridDim.x;
  const int cpx = nwg >> 3;
  const int bid = blockIdx.x;
  const int swz = (bid & 7) * cpx + (bid >> 3);
  const int mtiles = M >> 8;
  const int m0 = (swz % mtiles) * 256;
  const int n0 = (swz / mtiles) * (FN * 64);

  const int NT = K >> 6;

  const int rsw = (l15 & 7) << 4;
  const int a_base = (wm * 64 + l15) * 128;
  const int b_base = (wn * FN * 16 + l15) * 128;
  const int c0 = (l4 * 16) ^ rsw;
  const int c1 = (64 + l4 * 16) ^ rsw;

  const int st_row = l >> 3;
  const int st_k8 = (l & 7) ^ st_row;

  auto stA = [&](int tt, int h) {
    if (tt >= NT) return;
    const unsigned short* g = A + (size_t)(m0 + h * 128) * K + tt * 64 + st_k8 * 8;
    unsigned short* lb = (unsigned short*)(Sc + (tt & 1) * 32768 + h * 16384);
#pragma unroll
    for (int j = 0; j < 2; ++j) {
      int blk = j * 8 + wvid;
      gl16(g + (size_t)(blk * 8 + st_row) * K, lb + blk * 512);
    }
  };
  auto stB = [&](int tt) {
    if (tt >= NT) return;
    const unsigned short* g = B + (size_t)n0 * K + tt * 64 + st_k8 * 8;
    unsigned short* lb = (unsigned short*)(Sc + 65536 + (tt & 1) * (FN * 8192));
#pragma unroll
    for (int j = 0; j < FN; ++j) {
      int blk = j * 8 + wvid;
      gl16(g + (size_t)(blk * 8 + st_row) * K, lb + blk * 512);
    }
  };

  f32x4 acc[2][4][FN] = {};

  stA(0, 0); stA(0, 1); stB(0);
  stA(1, 0); stA(1, 1);
  if (NT > 1) asm volatile("s_waitcnt vmcnt(4)" ::: "memory");
  else        asm volatile("s_waitcnt vmcnt(0)" ::: "memory");
  __builtin_amdgcn_s_barrier();

  for (int t = 0; t < NT; ++t) {
    const int b = t & 1;
    const char* Ab = Sc + b * 32768;
    const char* Bb = Sc + 65536 + b * (FN * 8192);
    bf16x8 a[4][2], bb[FN][2];

#pragma unroll
    for (int fm = 0; fm < 4; ++fm) {
      a[fm][0] = *(const bf16x8*)(Ab + a_base + fm * 2048 + c0);
      a[fm][1] = *(const bf16x8*)(Ab + a_base + fm * 2048 + c1);
    }
#pragma unroll
    for (int fn = 0; fn < FN; ++fn) {
      bb[fn][0] = *(const bf16x8*)(Bb + b_base + fn * 2048 + c0);
      bb[fn][1] = *(const bf16x8*)(Bb + b_base + fn * 2048 + c1);
    }
    stB(t + 1);
    __builtin_amdgcn_s_barrier();
    __builtin_amdgcn_s_setprio(1);
#pragma unroll
    for (int fm = 0; fm < 4; ++fm)
#pragma unroll
      for (int fn = 0; fn < FN; ++fn)
#pragma unroll
        for (int ks = 0; ks < 2; ++ks)
          acc[0][fm][fn] = __builtin_amdgcn_mfma_f32_16x16x32_bf16(a[fm][ks], bb[fn][ks], acc[0][fm][fn], 0, 0, 0);
    __builtin_amdgcn_s_setprio(0);
    __builtin_amdgcn_s_barrier();

#pragma unroll
    for (int fm = 0; fm < 4; ++fm) {
      a[fm][0] = *(const bf16x8*)(Ab + 16384 + a_base + fm * 2048 + c0);
      a[fm][1] = *(const bf16x8*)(Ab + 16384 + a_base + fm * 2048 + c1);
    }
    stA(t + 2, 0);
    __builtin_amdgcn_s_barrier();
    __builtin_amdgcn_s_setprio(1);
#pragma unroll
    for (int fm = 0; fm < 4; ++fm)
#pragma unroll
      for (int fn = 0; fn < FN; ++fn)
#pragma unroll
        for (int ks = 0; ks < 2; ++ks)
          acc[1][fm][fn] = __builtin_amdgcn_mfma_f32_16x16x32_bf16(a[fm][ks], bb[fn][ks], acc[1][fm][fn], 0, 0, 0);
    __builtin_amdgcn_s_setprio(0);
    __builtin_amdgcn_s_barrier();

    stA(t + 2, 1);
    if (t + 1 < NT) {
      if (t + 1 == NT - 1) asm volatile("s_waitcnt vmcnt(0)" ::: "memory");
      else                 asm volatile("s_waitcnt vmcnt(4)" ::: "memory");
      __builtin_amdgcn_s_barrier();
    }
  }

#pragma unroll
  for (int h = 0; h < 2; ++h)
#pragma unroll
    for (int fm = 0; fm < 4; ++fm) {
      int row0 = m0 + h * 128 + wm * 64 + fm * 16 + l4 * 4;
#pragma unroll
      for (int fn = 0; fn < FN; ++fn) {
        int col = n0 + wn * FN * 16 + fn * 16 + l15;
#pragma unroll
        for (int r = 0; r < 4; ++r)
          C[(size_t)(row0 + r) * N + col] = acc[h][fm][fn][r];
      }
    }
}

// ------------- RoPE + int8 quantize; dequant scales stored TRANSPOSED [h][s] -------------
__global__ __launch_bounds__(256) void k_ropequant(const float* __restrict__ qkv,
                                                   const float* __restrict__ cost,
                                                   const float* __restrict__ sint,
                                                   unsigned short* __restrict__ q_int,
                                                   float* __restrict__ q_ds_t,
                                                   unsigned short* __restrict__ k_int,
                                                   float* __restrict__ k_ds_t,
                                                   unsigned short* __restrict__ v_bf) {
  int s = blockIdx.x;
  int wv = threadIdx.x >> 6, l = threadIdx.x & 63;
  int hh = blockIdx.y * 4 + wv;  // 0..47: [0,32) q, [32,40) k, [40,48) v
  const float* row = qkv + (size_t)s * NQKV;
  if (hh < NH + NKV) {
    int off = (hh < NH) ? hh * HD : DMODEL + (hh - NH) * HD;
    float t1 = row[off + l], t2 = row[off + 64 + l];
    float c1 = cost[s * HD + l],      sn1 = sint[s * HD + l];
    float c2 = cost[s * HD + 64 + l], sn2 = sint[s * HD + 64 + l];
    float o1 = t1 * c1 - t2 * sn1;
    float o2 = t2 * c2 + t1 * sn2;
    float amax = fmaxf(fabsf(o1), fabsf(o2));
#pragma unroll
    for (int m = 1; m < 64; m <<= 1) amax = fmaxf(amax, __shfl_xor(amax, m));
    amax = fmaxf(amax, 1e-5f);
    float scale = 127.0f / amax;
    float dscale = amax * (1.0f / 127.0f);
    float v1 = fminf(fmaxf(rintf(o1 * scale), -128.f), 127.f);
    float v2 = fminf(fmaxf(rintf(o2 * scale), -128.f), 127.f);
    if (hh < NH) {
      unsigned short* dst = q_int + ((size_t)s * NH + hh) * HD;
      dst[l] = f2b(v1); dst[l + 64] = f2b(v2);
      if (l == 0) q_ds_t[(size_t)hh * S_LEN + s] = dscale;
    } else {
      int kh = hh - NH;
      unsigned short* dst = k_int + ((size_t)s * NKV + kh) * HD;
      dst[l] = f2b(v1); dst[l + 64] = f2b(v2);
      if (l == 0) k_ds_t[(size_t)kh * S_LEN + s] = dscale;
    }
  } else {
    int vh = hh - (NH + NKV);
    const float* src = row + DMODEL + NKV * HD + vh * HD;
    unsigned short* dst = v_bf + ((size_t)s * NKV + vh) * HD;
    dst[l] = f2b(src[l]);
    dst[l + 64] = f2b(src[l + 64]);
  }
}

// ------------- causal GQA flash attention: 2 heads/block (shared K/V), swapped QK^T -------------
// 512 blocks: kvh=bid&7 (XCD-pinned), head pair, qt LPT-ordered; K,V dbuf in LDS (async gl16,
// XOR-swizzled); softmax in log2 domain, per-lane row (q=l15) after swapped mfma(K,Q);
// T13 defer-max; P via 4x ds_write_b64 of native __bf16 casts.
__global__ __launch_bounds__(256) void k_attn(const unsigned short* __restrict__ q_int,
                                              const float* __restrict__ q_ds_t,
                                              const unsigned short* __restrict__ k_int,
                                              const float* __restrict__ k_ds_t,
                                              const unsigned short* __restrict__ v_t,
                                              unsigned short* __restrict__ o_bf) {
  __shared__ __align__(16) unsigned short K_lds[2][8192];
  __shared__ __align__(16) unsigned short V_lds[2][8192];
  __shared__ __align__(16) unsigned short P_lds[4][16 * 72];

  const int bid = blockIdx.x;
  const int kvh = bid & 7;                    // XCD-pinned K/V
  const int ha = kvh * 4 + ((bid >> 3) & 1) * 2;  // head pair base
  const int qt = 31 - (bid >> 4);             // LPT: longest first
  const int tid = threadIdx.x, wv = tid >> 6, l = tid & 63;
  const int l15 = l & 15, l4 = l >> 4;

  auto stage = [&](int b, int kt) {
    const unsigned short* kB = k_int + (size_t)kt * 64 * (NKV * HD) + kvh * HD;
    const unsigned short* vB = v_t + (size_t)kvh * HD * S_LEN + (size_t)kt * 64;
#pragma unroll
    for (int j = 0; j < 4; ++j) {
      int wi = j * 4 + wv;
      int slot = wi * 64 + l;
      int key = slot >> 4;
      int colb = ((slot & 15) * 16) ^ ((key & 7) << 4);
      gl16(kB + key * (NKV * HD) + (colb >> 1), &K_lds[b][wi * 512]);
      int d = slot >> 3;
      int ckb = ((slot & 7) * 16) ^ ((d & 7) << 4);
      gl16(vB + (size_t)d * S_LEN + (ckb >> 1), &V_lds[b][wi * 512]);
    }
  };

  const int qrow_lo = qt * 64 + wv * 16;
  const int qg = qrow_lo + l15;       // this lane's softmax row (swapped layout)
  const int crow = qrow_lo + l4 * 4;  // PV output row base (C layout)

  bf16x8 qf[2][4];
  float qsS[2];
#pragma unroll
  for (int h2 = 0; h2 < 2; ++h2) {
    const unsigned short* qp = q_int + ((size_t)(qrow_lo + l15) * NH + ha + h2) * HD + l4 * 8;
#pragma unroll
    for (int kd = 0; kd < 4; ++kd) qf[h2][kd] = *(const bf16x8*)(qp + kd * 32);
    qsS[h2] = ATT_SCALE_L2E * q_ds_t[(size_t)(ha + h2) * S_LEN + qg];
  }

  float m_run[2] = {-3.0e38f, -3.0e38f};
  float l_run[2] = {0.f, 0.f};
  f32x4 o_acc[2][8] = {};

  const int nkt = qt + 1;
  stage(0, 0);
  __syncthreads();  // tile 0 staged

  for (int kt = 0; kt < nkt; ++kt) {
    const int cur = kt & 1;
    // k dequant scales: float4 per key-16-group (transposed layout, L2-hot broadcast)
    f32x4 ksd[4];
    {
      const f32x4* kdp = (const f32x4*)(k_ds_t + (size_t)kvh * S_LEN + kt * 64 + l4 * 4);
#pragma unroll
      for (int nt = 0; nt < 4; ++nt) ksd[nt] = kdp[nt * 4];
    }
    if (kt + 1 < nkt) stage(cur ^ 1, kt + 1);

    // ---- swapped QK^T: mfma(K,Q) -> S[key][q], q on lane axis; kf shared by both heads ----
    f32x4 sacc[2][4] = {};
#pragma unroll
    for (int nt = 0; nt < 4; ++nt) {
      int key = nt * 16 + l15;
#pragma unroll
      for (int kd = 0; kd < 4; ++kd) {
        int byte = key * 256 + kd * 64 + l4 * 16;
        byte ^= (key & 7) << 4;
        bf16x8 kf = *(const bf16x8*)((const char*)&K_lds[cur][0] + byte);
        sacc[0][nt] = __builtin_amdgcn_mfma_f32_16x16x32_bf16(kf, qf[0][kd], sacc[0][nt], 0, 0, 0);
        sacc[1][nt] = __builtin_amdgcn_mfma_f32_16x16x32_bf16(kf, qf[1][kd], sacc[1][nt], 0, 0, 0);
      }
    }

    bf16x8 pa[2][2];
#pragma unroll
    for (int h2 = 0; h2 < 2; ++h2) {
      // scale + causal mask; per-lane row q=l15, keys = kt*64 + nt*16 + l4*4 + r
      float p[4][4];
      float tmax = -3.0e38f;
#pragma unroll
      for (int nt = 0; nt < 4; ++nt) {
        int keyb = kt * 64 + nt * 16 + l4 * 4;
#pragma unroll
        for (int r = 0; r < 4; ++r) {
          float sc = sacc[h2][nt][r] * (qsS[h2] * ksd[nt][r]);
          sc = (keyb + r <= qg) ? sc : -3.0e38f;
          p[nt][r] = sc;
          tmax = fmaxf(tmax, sc);
        }
      }
      tmax = fmaxf(tmax, __shfl_xor(tmax, 16));
      tmax = fmaxf(tmax, __shfl_xor(tmax, 32));

      // T13 defer-max (log2 domain, 2^11 headroom)
      float nm = fmaxf(m_run[h2], tmax);
      bool need = tmax > m_run[h2] + 11.0f;
      if (__ballot(need)) {
        float corr = __builtin_amdgcn_exp2f(m_run[h2] - nm);
        m_run[h2] = nm;
        l_run[h2] *= corr;
        float cq[4];
#pragma unroll
        for (int r = 0; r < 4; ++r) cq[r] = __shfl(corr, (l & 48) | (l4 * 4 + r));
#pragma unroll
        for (int dt = 0; dt < 8; ++dt)
#pragma unroll
          for (int r = 0; r < 4; ++r) o_acc[h2][dt][r] *= cq[r];
      }

      float psum = 0.f;
#pragma unroll
      for (int nt = 0; nt < 4; ++nt)
#pragma unroll
        for (int r = 0; r < 4; ++r) {
          float e = __builtin_amdgcn_exp2f(p[nt][r] - m_run[h2]);
          p[nt][r] = e;
          psum += e;
        }
      psum += __shfl_xor(psum, 16);
      psum += __shfl_xor(psum, 32);
      l_run[h2] += psum;

      // P -> per-wave LDS: row q=l15, 4x b64 writes of 4 consecutive keys
#pragma unroll
      for (int nt = 0; nt < 4; ++nt) {
        bf16x4 pk;
        pk[0] = (__bf16)p[nt][0]; pk[1] = (__bf16)p[nt][1];
        pk[2] = (__bf16)p[nt][2]; pk[3] = (__bf16)p[nt][3];
        *(bf16x4*)((char*)&P_lds[wv][0] + l15 * 144 + nt * 32 + l4 * 8) = pk;
      }
#pragma unroll
      for (int kc = 0; kc < 2; ++kc)
        pa[h2][kc] = *(const bf16x8*)((const char*)&P_lds[wv][0] + l15 * 144 + kc * 64 + l4 * 16);
    }

    // ---- PV: vb shared by both heads ----
#pragma unroll
    for (int dt = 0; dt < 8; ++dt) {
      int d = dt * 16 + l15;
      int swzv = (d & 7) << 4;
#pragma unroll
      for (int kc = 0; kc < 2; ++kc) {
        int byte = d * 128 + ((kc * 64 + l4 * 16) ^ swzv);
        bf16x8 vb = *(const bf16x8*)((const char*)&V_lds[cur][0] + byte);
        o_acc[0][dt] = __builtin_amdgcn_mfma_f32_16x16x32_bf16(pa[0][kc], vb, o_acc[0][dt], 0, 0, 0);
        o_acc[1][dt] = __builtin_amdgcn_mfma_f32_16x16x32_bf16(pa[1][kc], vb, o_acc[1][dt], 0, 0, 0);
      }
    }
    __syncthreads();  // next tile staged; orders K/V buffer reuse
  }

#pragma unroll
  for (int h2 = 0; h2 < 2; ++h2) {
    float inv = 1.0f / l_run[h2];
    float invq[4];
#pragma unroll
    for (int r = 0; r < 4; ++r) invq[r] = __shfl(inv, (l & 48) | (l4 * 4 + r));
#pragma unroll
    for (int dt = 0; dt < 8; ++dt)
#pragma unroll
      for (int r = 0; r < 4; ++r)
        o_bf[(size_t)(crow + r) * (NH * HD) + (ha + h2) * HD + dt * 16 + l15] =
            f2b(o_acc[h2][dt][r] * invq[r]);
  }
}

extern "C" void kernel_launch(void* const* d_in, const int* in_sizes, int n_in,
                              void* d_out, int out_size, void* d_ws, size_t ws_size,
                              hipStream_t stream) {
  const float* x    = (const float*)d_in[0];
  const float* Wq   = (const float*)d_in[1];
  const float* Wk   = (const float*)d_in[2];
  const float* Wv   = (const float*)d_in[3];
  const float* Wo   = (const float*)d_in[4];
  const float* cost = (const float*)d_in[5];
  const float* sint = (const float*)d_in[6];
  float* out = (float*)d_out;
  char* ws = (char*)d_ws;

  unsigned short* xb     = (unsigned short*)(ws);                 // 16 MB (dead after gemm1)
  unsigned short* wqkv_t = (unsigned short*)(ws + 16777216);      // 48 MB (dead after gemm1)
  unsigned short* wo_t   = (unsigned short*)(ws + 67108864);      // 32 MB (4096x4096)
  float*          qkv    = (float*)(ws + 100663296);              // 48 MB (dead after ropequant)
  unsigned short* q_int  = (unsigned short*)(ws + 150994944);     // 16 MB
  unsigned short* k_int  = (unsigned short*)(ws + 167772160);     // 4 MB
  unsigned short* v_bf   = (unsigned short*)(ws + 171966464);     // 4 MB
  float*          q_ds_t = (float*)(ws + 176160768);              // 256 KB [NH][S]
  float*          k_ds_t = (float*)(ws + 176422912);              // 64 KB  [NKV][S]
  unsigned short* o_bf   = (unsigned short*)(ws + 176488448);     // 16 MB
  unsigned short* v_t    = (unsigned short*)(ws);                 // 4 MB, aliases dead xb

  hipFuncSetAttribute((const void*)k_gemmN<3>,
                      hipFuncAttributeMaxDynamicSharedMemorySize, 114688);
  hipFuncSetAttribute((const void*)k_gemmN<2>,
                      hipFuncAttributeMaxDynamicSharedMemorySize, 98304);

  k_cvt_x<<<(S_LEN * DMODEL / 4) / 256, 256, 0, stream>>>(x, xb);
  k_transpose<<<dim3(64, 64), 256, 0, stream>>>(Wq, wqkv_t, 4096, 4096);
  k_transpose<<<dim3(64, 16), 256, 0, stream>>>(Wk, wqkv_t + (size_t)4096 * 4096, 4096, 1024);
  k_transpose<<<dim3(64, 16), 256, 0, stream>>>(Wv, wqkv_t + (size_t)5120 * 4096, 4096, 1024);
  k_transpose<<<dim3(64, 64), 256, 0, stream>>>(Wo, wo_t, 4096, 4096);
  // QKV proj: 256x192 tiles -> 8 x 32 = 256 blocks = exact full-CU fill
  k_gemmN<3><<<dim3(256), 512, 114688, stream>>>(xb, wqkv_t, qkv, 2048, 6144, 4096);
  k_ropequant<<<dim3(2048, 12), 256, 0, stream>>>(qkv, cost, sint, q_int, q_ds_t, k_int, k_ds_t, v_bf);
  k_vt<<<dim3(32, 2, 8), 256, 0, stream>>>(v_bf, v_t);
  // attention: 512 blocks (2 heads each, shared K/V), LPT order, 2 blocks/CU
  k_attn<<<dim3(512), 256, 0, stream>>>(q_int, q_ds_t, k_int, k_ds_t, v_t, o_bf);
  // out proj: 256x128 tiles -> 8 x 32 = 256 blocks = exact full-CU fill
  k_gemmN<2><<<dim3(256), 512, 98304, stream>>>(o_bf, wo_t, out, 2048, 4096, 4096);
}

// Round 9
// 338.691 us; speedup vs baseline: 1.3052x; 1.0060x over previous
//
#include <hip/hip_runtime.h>
#include <hip/hip_bf16.h>

#define S_LEN 2048
#define DMODEL 4096
#define NH 32
#define NKV 8
#define HD 128
#define NQKV 6144
// 1/sqrt(128) * log2(e): scores in log2 domain so v_exp_f32 (=2^x) is the exp
#define ATT_SCALE_L2E 0.1275175213528852f

typedef __bf16 bf16x8 __attribute__((ext_vector_type(8)));
typedef __bf16 bf16x4 __attribute__((ext_vector_type(4)));
typedef float f32x4 __attribute__((ext_vector_type(4)));

// float -> bf16 bits, round-to-nearest-even
__device__ __forceinline__ unsigned short f2b(float f) {
  union { float f; unsigned u; } a; a.f = f;
  unsigned u = a.u;
  return (unsigned short)((u + 0x7FFFu + ((u >> 16) & 1u)) >> 16);
}
// bf16 bits -> float
__device__ __forceinline__ float b2f(unsigned short u) {
  union { unsigned u; float f; } a; a.u = (unsigned)u << 16; return a.f;
}

__device__ __forceinline__ void gl16(const unsigned short* g, unsigned short* l) {
  __builtin_amdgcn_global_load_lds(
      (const __attribute__((address_space(1))) unsigned int*)g,
      (__attribute__((address_space(3))) unsigned int*)l, 16, 0, 0);
}

// ---------------- x fp32 -> bf16 ----------------
__global__ __launch_bounds__(256) void k_cvt_x(const float* __restrict__ x,
                                               unsigned short* __restrict__ xb) {
  int i = blockIdx.x * 256 + threadIdx.x;
  float4 v = ((const float4*)x)[i];
  ushort4 o;
  o.x = f2b(v.x); o.y = f2b(v.y); o.z = f2b(v.z); o.w = f2b(v.w);
  ((ushort4*)xb)[i] = o;
}

// ------------- W (K,N) fp32 -> Wt (N,K) bf16, ushort4 stores -------------
__global__ __launch_bounds__(256) void k_transpose(const float* __restrict__ W,
                                                   unsigned short* __restrict__ Wt,
                                                   int K, int N) {
  __shared__ float tile[64][65];
  int k0 = blockIdx.x * 64, n0 = blockIdx.y * 64;
  int tx = threadIdx.x & 31, ty = threadIdx.x >> 5;
#pragma unroll
  for (int i = 0; i < 8; ++i) {
    int k = ty + i * 8;
    const float* src = W + (size_t)(k0 + k) * N + n0;
    tile[k][tx] = src[tx];
    tile[k][tx + 32] = src[tx + 32];
  }
  __syncthreads();
  int kq = threadIdx.x & 15, nb = threadIdx.x >> 4;
#pragma unroll
  for (int i = 0; i < 4; ++i) {
    int n = nb + i * 16;
    ushort4 o;
    o.x = f2b(tile[kq * 4 + 0][n]);
    o.y = f2b(tile[kq * 4 + 1][n]);
    o.z = f2b(tile[kq * 4 + 2][n]);
    o.w = f2b(tile[kq * 4 + 3][n]);
    *(ushort4*)&Wt[(size_t)(n0 + n) * K + k0 + kq * 4] = o;
  }
}

// ------------- V [S][NKV][HD] bf16 -> V^T [NKV][HD][S] bf16 -------------
__global__ __launch_bounds__(256) void k_vt(const unsigned short* __restrict__ v_bf,
                                            unsigned short* __restrict__ v_t) {
  __shared__ unsigned short tile[64][65];
  int s0 = blockIdx.x * 64, d0 = blockIdx.y * 64, kvh = blockIdx.z;
  int tx = threadIdx.x & 63, ty = threadIdx.x >> 6;
#pragma unroll
  for (int i = 0; i < 16; ++i) {
    int s = ty + i * 4;
    tile[s][tx] = v_bf[((size_t)(s0 + s) * NKV + kvh) * HD + d0 + tx];
  }
  __syncthreads();
#pragma unroll
  for (int i = 0; i < 16; ++i) {
    int d = ty + i * 4;
    v_t[((size_t)kvh * HD + d0 + d) * S_LEN + s0 + tx] = tile[tx][d];
  }
}

// ============ 128 x (FN*64) GEMM, 2 blocks/CU: C = A(MxK) * Bt(NxK), bf16 in ============
// BM=128, BN=FN*64, BK=64, 512 threads = 8 waves (2Mx4N); per-wave output 64 x FN*16.
// LDS (32 + FN*16) KB -> FN=3: 80 KB = exactly 2 blocks/CU; grid 16x32=512 = 2/CU.
// Two INDEPENDENT blocks per CU overlap barrier/read phases with MFMA phases.
// G4 swizzle via pre-swizzled gl16 source + swizzled ds_read col. Boundary vmcnt(2)
// leaves exactly the 2 stA(t+2) units in flight. ks-split compute keeps VGPR <= 128.
template <int FN, bool BF16OUT>
__global__ __launch_bounds__(512, 4) void k_g128(const unsigned short* __restrict__ A,
                                                 const unsigned short* __restrict__ B,
                                                 void* __restrict__ Cv,
                                                 int M, int N, int K) {
  extern __shared__ __align__(16) unsigned short smem[];
  char* Sc = (char*)smem;
  const int tid = threadIdx.x;
  const int wvid = tid >> 6, l = tid & 63;
  const int wm = wvid >> 2, wn = wvid & 3;
  const int l15 = l & 15, l4 = l >> 4;

  // XCD-bijective swizzle (nwg = 512)
  const int cpx = gridDim.x >> 3;
  const int swz = (blockIdx.x & 7) * cpx + (blockIdx.x >> 3);
  const int mtiles = M >> 7;
  const int m0 = (swz % mtiles) * 128;
  const int n0 = (swz / mtiles) * (FN * 64);

  const int NT = K >> 6;

  const int rsw = (l15 & 7) << 4;
  const int a_base = (wm * 64 + l15) * 128;        // + fm*2048 + c{0,1}
  const int b_base = (wn * FN * 16 + l15) * 128;   // + fn*2048 + c{0,1}
  const int c0 = (l4 * 16) ^ rsw;
  const int c1 = (64 + l4 * 16) ^ rsw;

  // stage: dest row = j*64 + wvid*8 + (l>>3), slot = l&7; source k8 pre-swizzled
  const int srow = l >> 3;
  const int st_k8 = (l & 7) ^ (srow & 7);

  auto stA = [&](int tt) {  // 16 KB: 2 gl16/thread
    if (tt >= NT) return;
    const unsigned short* g = A + (size_t)(m0 + wvid * 8 + srow) * K + tt * 64 + st_k8 * 8;
    char* lb = Sc + (tt & 1) * 16384 + wvid * 1024;
#pragma unroll
    for (int j = 0; j < 2; ++j)
      gl16(g + (size_t)(j * 64) * K, (unsigned short*)(lb + j * 8192));
  };
  auto stB = [&](int tt) {  // FN*8 KB: FN gl16/thread
    if (tt >= NT) return;
    const unsigned short* g = B + (size_t)(n0 + wvid * 8 + srow) * K + tt * 64 + st_k8 * 8;
    char* lb = Sc + 32768 + (tt & 1) * (FN * 8192) + wvid * 1024;
#pragma unroll
    for (int j = 0; j < FN; ++j)
      gl16(g + (size_t)(j * 64) * K, (unsigned short*)(lb + j * 8192));
  };

  f32x4 acc[4][FN] = {};

  // prologue: t0 fully, t1's A
  stA(0); stB(0); stA(1);
  if (NT > 1) asm volatile("s_waitcnt vmcnt(2)" ::: "memory");
  else        asm volatile("s_waitcnt vmcnt(0)" ::: "memory");
  __builtin_amdgcn_s_barrier();

  for (int t = 0; t < NT; ++t) {
    const char* Ab = Sc + (t & 1) * 16384;
    const char* Bb = Sc + 32768 + (t & 1) * (FN * 8192);
    stB(t + 1);  // async into other B buffer
    bf16x8 a[4], b[FN];
    // ---- ks0 ----
#pragma unroll
    for (int fm = 0; fm < 4; ++fm) a[fm] = *(const bf16x8*)(Ab + a_base + fm * 2048 + c0);
#pragma unroll
    for (int fn = 0; fn < FN; ++fn) b[fn] = *(const bf16x8*)(Bb + b_base + fn * 2048 + c0);
    __builtin_amdgcn_s_setprio(1);
#pragma unroll
    for (int fm = 0; fm < 4; ++fm)
#pragma unroll
      for (int fn = 0; fn < FN; ++fn)
        acc[fm][fn] = __builtin_amdgcn_mfma_f32_16x16x32_bf16(a[fm], b[fn], acc[fm][fn], 0, 0, 0);
    __builtin_amdgcn_s_setprio(0);
    // ---- ks1 ----
#pragma unroll
    for (int fm = 0; fm < 4; ++fm) a[fm] = *(const bf16x8*)(Ab + a_base + fm * 2048 + c1);
#pragma unroll
    for (int fn = 0; fn < FN; ++fn) b[fn] = *(const bf16x8*)(Bb + b_base + fn * 2048 + c1);
    __builtin_amdgcn_s_setprio(1);
#pragma unroll
    for (int fm = 0; fm < 4; ++fm)
#pragma unroll
      for (int fn = 0; fn < FN; ++fn)
        acc[fm][fn] = __builtin_amdgcn_mfma_f32_16x16x32_bf16(a[fm], b[fn], acc[fm][fn], 0, 0, 0);
    __builtin_amdgcn_s_setprio(0);
    __builtin_amdgcn_s_barrier();  // all waves done reading buf t
    stA(t + 2);                    // overwrite A buf (t&1) for t+2
    if (t + 1 < NT) {
      if (t + 1 == NT - 1) asm volatile("s_waitcnt vmcnt(0)" ::: "memory");
      else                 asm volatile("s_waitcnt vmcnt(2)" ::: "memory");
      __builtin_amdgcn_s_barrier();
    }
  }

  // epilogue
#pragma unroll
  for (int fm = 0; fm < 4; ++fm) {
    int row0 = m0 + wm * 64 + fm * 16 + l4 * 4;
#pragma unroll
    for (int fn = 0; fn < FN; ++fn) {
      int col = n0 + wn * FN * 16 + fn * 16 + l15;
#pragma unroll
      for (int r = 0; r < 4; ++r) {
        if constexpr (BF16OUT)
          ((unsigned short*)Cv)[(size_t)(row0 + r) * N + col] = f2b(acc[fm][fn][r]);
        else
          ((float*)Cv)[(size_t)(row0 + r) * N + col] = acc[fm][fn][r];
      }
    }
  }
}

// ============ 256 x (FN*64) 2-phase GEMM (round-7 proven) — used for out-proj ============
template <int FN>
__global__ __launch_bounds__(512, 2) void k_gemmN(const unsigned short* __restrict__ A,
                                                  const unsigned short* __restrict__ B,
                                                  float* __restrict__ C,
                                                  int M, int N, int K) {
  extern __shared__ __align__(16) unsigned short smem[];
  char* Sc = (char*)smem;
  const int tid = threadIdx.x;
  const int wvid = tid >> 6, l = tid & 63;
  const int wm = wvid >> 2, wn = wvid & 3;
  const int l15 = l & 15, l4 = l >> 4;

  const int nwg = gridDim.x;
  const int cpx = nwg >> 3;
  const int bid = blockIdx.x;
  const int swz = (bid & 7) * cpx + (bid >> 3);
  const int mtiles = M >> 8;
  const int m0 = (swz % mtiles) * 256;
  const int n0 = (swz / mtiles) * (FN * 64);

  const int NT = K >> 6;

  const int rsw = (l15 & 7) << 4;
  const int a_base = (wm * 64 + l15) * 128;
  const int b_base = (wn * FN * 16 + l15) * 128;
  const int c0 = (l4 * 16) ^ rsw;
  const int c1 = (64 + l4 * 16) ^ rsw;

  const int st_row = l >> 3;
  const int st_k8 = (l & 7) ^ st_row;

  auto stA = [&](int tt, int h) {
    if (tt >= NT) return;
    const unsigned short* g = A + (size_t)(m0 + h * 128) * K + tt * 64 + st_k8 * 8;
    unsigned short* lb = (unsigned short*)(Sc + (tt & 1) * 32768 + h * 16384);
#pragma unroll
    for (int j = 0; j < 2; ++j) {
      int blk = j * 8 + wvid;
      gl16(g + (size_t)(blk * 8 + st_row) * K, lb + blk * 512);
    }
  };
  auto stB = [&](int tt) {
    if (tt >= NT) return;
    const unsigned short* g = B + (size_t)n0 * K + tt * 64 + st_k8 * 8;
    unsigned short* lb = (unsigned short*)(Sc + 65536 + (tt & 1) * (FN * 8192));
#pragma unroll
    for (int j = 0; j < FN; ++j) {
      int blk = j * 8 + wvid;
      gl16(g + (size_t)(blk * 8 + st_row) * K, lb + blk * 512);
    }
  };

  f32x4 acc[2][4][FN] = {};

  stA(0, 0); stA(0, 1); stB(0);
  stA(1, 0); stA(1, 1);
  if (NT > 1) asm volatile("s_waitcnt vmcnt(4)" ::: "memory");
  else        asm volatile("s_waitcnt vmcnt(0)" ::: "memory");
  __builtin_amdgcn_s_barrier();

  for (int t = 0; t < NT; ++t) {
    const int b = t & 1;
    const char* Ab = Sc + b * 32768;
    const char* Bb = Sc + 65536 + b * (FN * 8192);
    bf16x8 a[4][2], bb[FN][2];

#pragma unroll
    for (int fm = 0; fm < 4; ++fm) {
      a[fm][0] = *(const bf16x8*)(Ab + a_base + fm * 2048 + c0);
      a[fm][1] = *(const bf16x8*)(Ab + a_base + fm * 2048 + c1);
    }
#pragma unroll
    for (int fn = 0; fn < FN; ++fn) {
      bb[fn][0] = *(const bf16x8*)(Bb + b_base + fn * 2048 + c0);
      bb[fn][1] = *(const bf16x8*)(Bb + b_base + fn * 2048 + c1);
    }
    stB(t + 1);
    __builtin_amdgcn_s_barrier();
    __builtin_amdgcn_s_setprio(1);
#pragma unroll
    for (int fm = 0; fm < 4; ++fm)
#pragma unroll
      for (int fn = 0; fn < FN; ++fn)
#pragma unroll
        for (int ks = 0; ks < 2; ++ks)
          acc[0][fm][fn] = __builtin_amdgcn_mfma_f32_16x16x32_bf16(a[fm][ks], bb[fn][ks], acc[0][fm][fn], 0, 0, 0);
    __builtin_amdgcn_s_setprio(0);
    __builtin_amdgcn_s_barrier();

#pragma unroll
    for (int fm = 0; fm < 4; ++fm) {
      a[fm][0] = *(const bf16x8*)(Ab + 16384 + a_base + fm * 2048 + c0);
      a[fm][1] = *(const bf16x8*)(Ab + 16384 + a_base + fm * 2048 + c1);
    }
    stA(t + 2, 0);
    __builtin_amdgcn_s_barrier();
    __builtin_amdgcn_s_setprio(1);
#pragma unroll
    for (int fm = 0; fm < 4; ++fm)
#pragma unroll
      for (int fn = 0; fn < FN; ++fn)
#pragma unroll
        for (int ks = 0; ks < 2; ++ks)
          acc[1][fm][fn] = __builtin_amdgcn_mfma_f32_16x16x32_bf16(a[fm][ks], bb[fn][ks], acc[1][fm][fn], 0, 0, 0);
    __builtin_amdgcn_s_setprio(0);
    __builtin_amdgcn_s_barrier();

    stA(t + 2, 1);
    if (t + 1 < NT) {
      if (t + 1 == NT - 1) asm volatile("s_waitcnt vmcnt(0)" ::: "memory");
      else                 asm volatile("s_waitcnt vmcnt(4)" ::: "memory");
      __builtin_amdgcn_s_barrier();
    }
  }

#pragma unroll
  for (int h = 0; h < 2; ++h)
#pragma unroll
    for (int fm = 0; fm < 4; ++fm) {
      int row0 = m0 + h * 128 + wm * 64 + fm * 16 + l4 * 4;
#pragma unroll
      for (int fn = 0; fn < FN; ++fn) {
        int col = n0 + wn * FN * 16 + fn * 16 + l15;
#pragma unroll
        for (int r = 0; r < 4; ++r)
          C[(size_t)(row0 + r) * N + col] = acc[h][fm][fn][r];
      }
    }
}

// ------------- RoPE + int8 quantize (qkv now bf16); dequant scales TRANSPOSED [h][s] -------------
__global__ __launch_bounds__(256) void k_ropequant(const unsigned short* __restrict__ qkv,
                                                   const float* __restrict__ cost,
                                                   const float* __restrict__ sint,
                                                   unsigned short* __restrict__ q_int,
                                                   float* __restrict__ q_ds_t,
                                                   unsigned short* __restrict__ k_int,
                                                   float* __restrict__ k_ds_t,
                                                   unsigned short* __restrict__ v_bf) {
  int s = blockIdx.x;
  int wv = threadIdx.x >> 6, l = threadIdx.x & 63;
  int hh = blockIdx.y * 4 + wv;  // 0..47: [0,32) q, [32,40) k, [40,48) v
  const unsigned short* row = qkv + (size_t)s * NQKV;
  if (hh < NH + NKV) {
    int off = (hh < NH) ? hh * HD : DMODEL + (hh - NH) * HD;
    float t1 = b2f(row[off + l]), t2 = b2f(row[off + 64 + l]);
    float c1 = cost[s * HD + l],      sn1 = sint[s * HD + l];
    float c2 = cost[s * HD + 64 + l], sn2 = sint[s * HD + 64 + l];
    float o1 = t1 * c1 - t2 * sn1;
    float o2 = t2 * c2 + t1 * sn2;
    float amax = fmaxf(fabsf(o1), fabsf(o2));
#pragma unroll
    for (int m = 1; m < 64; m <<= 1) amax = fmaxf(amax, __shfl_xor(amax, m));
    amax = fmaxf(amax, 1e-5f);
    float scale = 127.0f / amax;
    float dscale = amax * (1.0f / 127.0f);
    float v1 = fminf(fmaxf(rintf(o1 * scale), -128.f), 127.f);
    float v2 = fminf(fmaxf(rintf(o2 * scale), -128.f), 127.f);
    if (hh < NH) {
      unsigned short* dst = q_int + ((size_t)s * NH + hh) * HD;
      dst[l] = f2b(v1); dst[l + 64] = f2b(v2);
      if (l == 0) q_ds_t[(size_t)hh * S_LEN + s] = dscale;
    } else {
      int kh = hh - NH;
      unsigned short* dst = k_int + ((size_t)s * NKV + kh) * HD;
      dst[l] = f2b(v1); dst[l + 64] = f2b(v2);
      if (l == 0) k_ds_t[(size_t)kh * S_LEN + s] = dscale;
    }
  } else {
    int vh = hh - (NH + NKV);
    const unsigned short* src = row + DMODEL + NKV * HD + vh * HD;
    unsigned short* dst = v_bf + ((size_t)s * NKV + vh) * HD;
    dst[l] = src[l];
    dst[l + 64] = src[l + 64];
  }
}

// ------------- causal GQA flash attention (round-8 proven): 2 heads/block, swapped QK^T -------------
__global__ __launch_bounds__(256) void k_attn(const unsigned short* __restrict__ q_int,
                                              const float* __restrict__ q_ds_t,
                                              const unsigned short* __restrict__ k_int,
                                              const float* __restrict__ k_ds_t,
                                              const unsigned short* __restrict__ v_t,
                                              unsigned short* __restrict__ o_bf) {
  __shared__ __align__(16) unsigned short K_lds[2][8192];
  __shared__ __align__(16) unsigned short V_lds[2][8192];
  __shared__ __align__(16) unsigned short P_lds[4][16 * 72];

  const int bid = blockIdx.x;
  const int kvh = bid & 7;                    // XCD-pinned K/V
  const int ha = kvh * 4 + ((bid >> 3) & 1) * 2;  // head pair base
  const int qt = 31 - (bid >> 4);             // LPT: longest first
  const int tid = threadIdx.x, wv = tid >> 6, l = tid & 63;
  const int l15 = l & 15, l4 = l >> 4;

  auto stage = [&](int b, int kt) {
    const unsigned short* kB = k_int + (size_t)kt * 64 * (NKV * HD) + kvh * HD;
    const unsigned short* vB = v_t + (size_t)kvh * HD * S_LEN + (size_t)kt * 64;
#pragma unroll
    for (int j = 0; j < 4; ++j) {
      int wi = j * 4 + wv;
      int slot = wi * 64 + l;
      int key = slot >> 4;
      int colb = ((slot & 15) * 16) ^ ((key & 7) << 4);
      gl16(kB + key * (NKV * HD) + (colb >> 1), &K_lds[b][wi * 512]);
      int d = slot >> 3;
      int ckb = ((slot & 7) * 16) ^ ((d & 7) << 4);
      gl16(vB + (size_t)d * S_LEN + (ckb >> 1), &V_lds[b][wi * 512]);
    }
  };

  const int qrow_lo = qt * 64 + wv * 16;
  const int qg = qrow_lo + l15;
  const int crow = qrow_lo + l4 * 4;

  bf16x8 qf[2][4];
  float qsS[2];
#pragma unroll
  for (int h2 = 0; h2 < 2; ++h2) {
    const unsigned short* qp = q_int + ((size_t)(qrow_lo + l15) * NH + ha + h2) * HD + l4 * 8;
#pragma unroll
    for (int kd = 0; kd < 4; ++kd) qf[h2][kd] = *(const bf16x8*)(qp + kd * 32);
    qsS[h2] = ATT_SCALE_L2E * q_ds_t[(size_t)(ha + h2) * S_LEN + qg];
  }

  float m_run[2] = {-3.0e38f, -3.0e38f};
  float l_run[2] = {0.f, 0.f};
  f32x4 o_acc[2][8] = {};

  const int nkt = qt + 1;
  stage(0, 0);
  __syncthreads();

  for (int kt = 0; kt < nkt; ++kt) {
    const int cur = kt & 1;
    f32x4 ksd[4];
    {
      const f32x4* kdp = (const f32x4*)(k_ds_t + (size_t)kvh * S_LEN + kt * 64 + l4 * 4);
#pragma unroll
      for (int nt = 0; nt < 4; ++nt) ksd[nt] = kdp[nt * 4];
    }
    if (kt + 1 < nkt) stage(cur ^ 1, kt + 1);

    f32x4 sacc[2][4] = {};
#pragma unroll
    for (int nt = 0; nt < 4; ++nt) {
      int key = nt * 16 + l15;
#pragma unroll
      for (int kd = 0; kd < 4; ++kd) {
        int byte = key * 256 + kd * 64 + l4 * 16;
        byte ^= (key & 7) << 4;
        bf16x8 kf = *(const bf16x8*)((const char*)&K_lds[cur][0] + byte);
        sacc[0][nt] = __builtin_amdgcn_mfma_f32_16x16x32_bf16(kf, qf[0][kd], sacc[0][nt], 0, 0, 0);
        sacc[1][nt] = __builtin_amdgcn_mfma_f32_16x16x32_bf16(kf, qf[1][kd], sacc[1][nt], 0, 0, 0);
      }
    }

    bf16x8 pa[2][2];
#pragma unroll
    for (int h2 = 0; h2 < 2; ++h2) {
      float p[4][4];
      float tmax = -3.0e38f;
#pragma unroll
      for (int nt = 0; nt < 4; ++nt) {
        int keyb = kt * 64 + nt * 16 + l4 * 4;
#pragma unroll
        for (int r = 0; r < 4; ++r) {
          float sc = sacc[h2][nt][r] * (qsS[h2] * ksd[nt][r]);
          sc = (keyb + r <= qg) ? sc : -3.0e38f;
          p[nt][r] = sc;
          tmax = fmaxf(tmax, sc);
        }
      }
      tmax = fmaxf(tmax, __shfl_xor(tmax, 16));
      tmax = fmaxf(tmax, __shfl_xor(tmax, 32));

      float nm = fmaxf(m_run[h2], tmax);
      bool need = tmax > m_run[h2] + 11.0f;
      if (__ballot(need)) {
        float corr = __builtin_amdgcn_exp2f(m_run[h2] - nm);
        m_run[h2] = nm;
        l_run[h2] *= corr;
        float cq[4];
#pragma unroll
        for (int r = 0; r < 4; ++r) cq[r] = __shfl(corr, (l & 48) | (l4 * 4 + r));
#pragma unroll
        for (int dt = 0; dt < 8; ++dt)
#pragma unroll
          for (int r = 0; r < 4; ++r) o_acc[h2][dt][r] *= cq[r];
      }

      float psum = 0.f;
#pragma unroll
      for (int nt = 0; nt < 4; ++nt)
#pragma unroll
        for (int r = 0; r < 4; ++r) {
          float e = __builtin_amdgcn_exp2f(p[nt][r] - m_run[h2]);
          p[nt][r] = e;
          psum += e;
        }
      psum += __shfl_xor(psum, 16);
      psum += __shfl_xor(psum, 32);
      l_run[h2] += psum;

#pragma unroll
      for (int nt = 0; nt < 4; ++nt) {
        bf16x4 pk;
        pk[0] = (__bf16)p[nt][0]; pk[1] = (__bf16)p[nt][1];
        pk[2] = (__bf16)p[nt][2]; pk[3] = (__bf16)p[nt][3];
        *(bf16x4*)((char*)&P_lds[wv][0] + l15 * 144 + nt * 32 + l4 * 8) = pk;
      }
#pragma unroll
      for (int kc = 0; kc < 2; ++kc)
        pa[h2][kc] = *(const bf16x8*)((const char*)&P_lds[wv][0] + l15 * 144 + kc * 64 + l4 * 16);
    }

#pragma unroll
    for (int dt = 0; dt < 8; ++dt) {
      int d = dt * 16 + l15;
      int swzv = (d & 7) << 4;
#pragma unroll
      for (int kc = 0; kc < 2; ++kc) {
        int byte = d * 128 + ((kc * 64 + l4 * 16) ^ swzv);
        bf16x8 vb = *(const bf16x8*)((const char*)&V_lds[cur][0] + byte);
        o_acc[0][dt] = __builtin_amdgcn_mfma_f32_16x16x32_bf16(pa[0][kc], vb, o_acc[0][dt], 0, 0, 0);
        o_acc[1][dt] = __builtin_amdgcn_mfma_f32_16x16x32_bf16(pa[1][kc], vb, o_acc[1][dt], 0, 0, 0);
      }
    }
    __syncthreads();
  }

#pragma unroll
  for (int h2 = 0; h2 < 2; ++h2) {
    float inv = 1.0f / l_run[h2];
    float invq[4];
#pragma unroll
    for (int r = 0; r < 4; ++r) invq[r] = __shfl(inv, (l & 48) | (l4 * 4 + r));
#pragma unroll
    for (int dt = 0; dt < 8; ++dt)
#pragma unroll
      for (int r = 0; r < 4; ++r)
        o_bf[(size_t)(crow + r) * (NH * HD) + (ha + h2) * HD + dt * 16 + l15] =
            f2b(o_acc[h2][dt][r] * invq[r]);
  }
}

extern "C" void kernel_launch(void* const* d_in, const int* in_sizes, int n_in,
                              void* d_out, int out_size, void* d_ws, size_t ws_size,
                              hipStream_t stream) {
  const float* x    = (const float*)d_in[0];
  const float* Wq   = (const float*)d_in[1];
  const float* Wk   = (const float*)d_in[2];
  const float* Wv   = (const float*)d_in[3];
  const float* Wo   = (const float*)d_in[4];
  const float* cost = (const float*)d_in[5];
  const float* sint = (const float*)d_in[6];
  float* out = (float*)d_out;
  char* ws = (char*)d_ws;

  unsigned short* xb     = (unsigned short*)(ws);                 // 16 MB (dead after gemm1)
  unsigned short* wqkv_t = (unsigned short*)(ws + 16777216);      // 48 MB (dead after gemm1)
  unsigned short* wo_t   = (unsigned short*)(ws + 67108864);      // 32 MB (4096x4096)
  unsigned short* qkv    = (unsigned short*)(ws + 100663296);     // 24 MB bf16 (dead after ropequant)
  unsigned short* q_int  = (unsigned short*)(ws + 150994944);     // 16 MB
  unsigned short* k_int  = (unsigned short*)(ws + 167772160);     // 4 MB
  unsigned short* v_bf   = (unsigned short*)(ws + 171966464);     // 4 MB
  float*          q_ds_t = (float*)(ws + 176160768);              // 256 KB [NH][S]
  float*          k_ds_t = (float*)(ws + 176422912);              // 64 KB  [NKV][S]
  unsigned short* o_bf   = (unsigned short*)(ws + 176488448);     // 16 MB
  unsigned short* v_t    = (unsigned short*)(ws);                 // 4 MB, aliases dead xb

  hipFuncSetAttribute((const void*)k_g128<3, true>,
                      hipFuncAttributeMaxDynamicSharedMemorySize, 81920);
  hipFuncSetAttribute((const void*)k_gemmN<2>,
                      hipFuncAttributeMaxDynamicSharedMemorySize, 98304);

  k_cvt_x<<<(S_LEN * DMODEL / 4) / 256, 256, 0, stream>>>(x, xb);
  k_transpose<<<dim3(64, 64), 256, 0, stream>>>(Wq, wqkv_t, 4096, 4096);
  k_transpose<<<dim3(64, 16), 256, 0, stream>>>(Wk, wqkv_t + (size_t)4096 * 4096, 4096, 1024);
  k_transpose<<<dim3(64, 16), 256, 0, stream>>>(Wv, wqkv_t + (size_t)5120 * 4096, 4096, 1024);
  k_transpose<<<dim3(64, 64), 256, 0, stream>>>(Wo, wo_t, 4096, 4096);
  // QKV proj: 128x192 tiles -> 16 x 32 = 512 blocks = exactly 2 blocks/CU; bf16 output
  k_g128<3, true><<<dim3(512), 512, 81920, stream>>>(xb, wqkv_t, qkv, 2048, 6144, 4096);
  k_ropequant<<<dim3(2048, 12), 256, 0, stream>>>(qkv, cost, sint, q_int, q_ds_t, k_int, k_ds_t, v_bf);
  k_vt<<<dim3(32, 2, 8), 256, 0, stream>>>(v_bf, v_t);
  // attention: 512 blocks (2 heads each, shared K/V), LPT order
  k_attn<<<dim3(512), 256, 0, stream>>>(q_int, q_ds_t, k_int, k_ds_t, v_t, o_bf);
  // out proj: 256x128 tiles -> 256 blocks full fill (round-7 proven)
  k_gemmN<2><<<dim3(256), 512, 98304, stream>>>(o_bf, wo_t, out, 2048, 4096, 4096);
}

// Round 10
// 330.609 us; speedup vs baseline: 1.3371x; 1.0244x over previous
//
#include <hip/hip_runtime.h>
#include <hip/hip_bf16.h>

#define S_LEN 2048
#define DMODEL 4096
#define NH 32
#define NKV 8
#define HD 128
#define NQKV 6144
// 1/sqrt(128) * log2(e): scores in log2 domain so v_exp_f32 (=2^x) is the exp
#define ATT_SCALE_L2E 0.1275175213528852f

typedef __bf16 bf16x8 __attribute__((ext_vector_type(8)));
typedef __bf16 bf16x4 __attribute__((ext_vector_type(4)));
typedef float f32x4 __attribute__((ext_vector_type(4)));

// float -> bf16 bits, round-to-nearest-even
__device__ __forceinline__ unsigned short f2b(float f) {
  union { float f; unsigned u; } a; a.f = f;
  unsigned u = a.u;
  return (unsigned short)((u + 0x7FFFu + ((u >> 16) & 1u)) >> 16);
}
// bf16 bits -> float
__device__ __forceinline__ float b2f(unsigned short u) {
  union { unsigned u; float f; } a; a.u = (unsigned)u << 16; return a.f;
}

__device__ __forceinline__ void gl16(const unsigned short* g, unsigned short* l) {
  __builtin_amdgcn_global_load_lds(
      (const __attribute__((address_space(1))) unsigned int*)g,
      (__attribute__((address_space(3))) unsigned int*)l, 16, 0, 0);
}

// ---------------- x fp32 -> bf16 ----------------
__global__ __launch_bounds__(256) void k_cvt_x(const float* __restrict__ x,
                                               unsigned short* __restrict__ xb) {
  int i = blockIdx.x * 256 + threadIdx.x;
  float4 v = ((const float4*)x)[i];
  ushort4 o;
  o.x = f2b(v.x); o.y = f2b(v.y); o.z = f2b(v.z); o.w = f2b(v.w);
  ((ushort4*)xb)[i] = o;
}

// ------------- W (K,N) fp32 -> Wt (N,K) bf16, ushort4 stores -------------
__global__ __launch_bounds__(256) void k_transpose(const float* __restrict__ W,
                                                   unsigned short* __restrict__ Wt,
                                                   int K, int N) {
  __shared__ float tile[64][65];
  int k0 = blockIdx.x * 64, n0 = blockIdx.y * 64;
  int tx = threadIdx.x & 31, ty = threadIdx.x >> 5;
#pragma unroll
  for (int i = 0; i < 8; ++i) {
    int k = ty + i * 8;
    const float* src = W + (size_t)(k0 + k) * N + n0;
    tile[k][tx] = src[tx];
    tile[k][tx + 32] = src[tx + 32];
  }
  __syncthreads();
  int kq = threadIdx.x & 15, nb = threadIdx.x >> 4;
#pragma unroll
  for (int i = 0; i < 4; ++i) {
    int n = nb + i * 16;
    ushort4 o;
    o.x = f2b(tile[kq * 4 + 0][n]);
    o.y = f2b(tile[kq * 4 + 1][n]);
    o.z = f2b(tile[kq * 4 + 2][n]);
    o.w = f2b(tile[kq * 4 + 3][n]);
    *(ushort4*)&Wt[(size_t)(n0 + n) * K + k0 + kq * 4] = o;
  }
}

// ------------- V [S][NKV][HD] bf16 -> V^T [NKV][HD][S] bf16 -------------
__global__ __launch_bounds__(256) void k_vt(const unsigned short* __restrict__ v_bf,
                                            unsigned short* __restrict__ v_t) {
  __shared__ unsigned short tile[64][65];
  int s0 = blockIdx.x * 64, d0 = blockIdx.y * 64, kvh = blockIdx.z;
  int tx = threadIdx.x & 63, ty = threadIdx.x >> 6;
#pragma unroll
  for (int i = 0; i < 16; ++i) {
    int s = ty + i * 4;
    tile[s][tx] = v_bf[((size_t)(s0 + s) * NKV + kvh) * HD + d0 + tx];
  }
  __syncthreads();
#pragma unroll
  for (int i = 0; i < 16; ++i) {
    int d = ty + i * 4;
    v_t[((size_t)kvh * HD + d0 + d) * S_LEN + s0 + tx] = tile[tx][d];
  }
}

// ============ 128 x (FN*64) GEMM, 2 blocks/CU: C = A(MxK) * Bt(NxK), bf16 in ============
// BM=128, BN=FN*64, BK=64, 512 threads = 8 waves (2Mx4N); per-wave output 64 x FN*16.
// LDS (32 + FN*16) KB -> FN=3: 80 KB, FN=2: 64 KB — both exactly 2 blocks/CU.
// Two INDEPENDENT blocks per CU overlap barrier/read phases with MFMA phases (m114).
// G4 swizzle via pre-swizzled gl16 source + swizzled ds_read col. Boundary vmcnt(2)
// leaves exactly the 2 stA(t+2) instrs in flight (FN-independent accounting).
template <int FN, bool BF16OUT>
__global__ __launch_bounds__(512, 4) void k_g128(const unsigned short* __restrict__ A,
                                                 const unsigned short* __restrict__ B,
                                                 void* __restrict__ Cv,
                                                 int M, int N, int K) {
  extern __shared__ __align__(16) unsigned short smem[];
  char* Sc = (char*)smem;
  const int tid = threadIdx.x;
  const int wvid = tid >> 6, l = tid & 63;
  const int wm = wvid >> 2, wn = wvid & 3;
  const int l15 = l & 15, l4 = l >> 4;

  // XCD-bijective swizzle (nwg = 512 at both call sites)
  const int cpx = gridDim.x >> 3;
  const int swz = (blockIdx.x & 7) * cpx + (blockIdx.x >> 3);
  const int mtiles = M >> 7;
  const int m0 = (swz % mtiles) * 128;
  const int n0 = (swz / mtiles) * (FN * 64);

  const int NT = K >> 6;

  const int rsw = (l15 & 7) << 4;
  const int a_base = (wm * 64 + l15) * 128;        // + fm*2048 + c{0,1}
  const int b_base = (wn * FN * 16 + l15) * 128;   // + fn*2048 + c{0,1}
  const int c0 = (l4 * 16) ^ rsw;
  const int c1 = (64 + l4 * 16) ^ rsw;

  // stage: dest row = j*64 + wvid*8 + (l>>3), slot = l&7; source k8 pre-swizzled
  const int srow = l >> 3;
  const int st_k8 = (l & 7) ^ (srow & 7);

  auto stA = [&](int tt) {  // 16 KB: 2 gl16/thread
    if (tt >= NT) return;
    const unsigned short* g = A + (size_t)(m0 + wvid * 8 + srow) * K + tt * 64 + st_k8 * 8;
    char* lb = Sc + (tt & 1) * 16384 + wvid * 1024;
#pragma unroll
    for (int j = 0; j < 2; ++j)
      gl16(g + (size_t)(j * 64) * K, (unsigned short*)(lb + j * 8192));
  };
  auto stB = [&](int tt) {  // FN*8 KB: FN gl16/thread
    if (tt >= NT) return;
    const unsigned short* g = B + (size_t)(n0 + wvid * 8 + srow) * K + tt * 64 + st_k8 * 8;
    char* lb = Sc + 32768 + (tt & 1) * (FN * 8192) + wvid * 1024;
#pragma unroll
    for (int j = 0; j < FN; ++j)
      gl16(g + (size_t)(j * 64) * K, (unsigned short*)(lb + j * 8192));
  };

  f32x4 acc[4][FN] = {};

  // prologue: t0 fully, t1's A
  stA(0); stB(0); stA(1);
  if (NT > 1) asm volatile("s_waitcnt vmcnt(2)" ::: "memory");
  else        asm volatile("s_waitcnt vmcnt(0)" ::: "memory");
  __builtin_amdgcn_s_barrier();

  for (int t = 0; t < NT; ++t) {
    const char* Ab = Sc + (t & 1) * 16384;
    const char* Bb = Sc + 32768 + (t & 1) * (FN * 8192);
    stB(t + 1);  // async into other B buffer
    bf16x8 a[4], b[FN];
    // ---- ks0 ----
#pragma unroll
    for (int fm = 0; fm < 4; ++fm) a[fm] = *(const bf16x8*)(Ab + a_base + fm * 2048 + c0);
#pragma unroll
    for (int fn = 0; fn < FN; ++fn) b[fn] = *(const bf16x8*)(Bb + b_base + fn * 2048 + c0);
    __builtin_amdgcn_s_setprio(1);
#pragma unroll
    for (int fm = 0; fm < 4; ++fm)
#pragma unroll
      for (int fn = 0; fn < FN; ++fn)
        acc[fm][fn] = __builtin_amdgcn_mfma_f32_16x16x32_bf16(a[fm], b[fn], acc[fm][fn], 0, 0, 0);
    __builtin_amdgcn_s_setprio(0);
    // ---- ks1 ----
#pragma unroll
    for (int fm = 0; fm < 4; ++fm) a[fm] = *(const bf16x8*)(Ab + a_base + fm * 2048 + c1);
#pragma unroll
    for (int fn = 0; fn < FN; ++fn) b[fn] = *(const bf16x8*)(Bb + b_base + fn * 2048 + c1);
    __builtin_amdgcn_s_setprio(1);
#pragma unroll
    for (int fm = 0; fm < 4; ++fm)
#pragma unroll
      for (int fn = 0; fn < FN; ++fn)
        acc[fm][fn] = __builtin_amdgcn_mfma_f32_16x16x32_bf16(a[fm], b[fn], acc[fm][fn], 0, 0, 0);
    __builtin_amdgcn_s_setprio(0);
    __builtin_amdgcn_s_barrier();  // all waves done reading buf t
    stA(t + 2);                    // overwrite A buf (t&1) for t+2
    if (t + 1 < NT) {
      if (t + 1 == NT - 1) asm volatile("s_waitcnt vmcnt(0)" ::: "memory");
      else                 asm volatile("s_waitcnt vmcnt(2)" ::: "memory");
      __builtin_amdgcn_s_barrier();
    }
  }

  // epilogue
#pragma unroll
  for (int fm = 0; fm < 4; ++fm) {
    int row0 = m0 + wm * 64 + fm * 16 + l4 * 4;
#pragma unroll
    for (int fn = 0; fn < FN; ++fn) {
      int col = n0 + wn * FN * 16 + fn * 16 + l15;
#pragma unroll
      for (int r = 0; r < 4; ++r) {
        if constexpr (BF16OUT)
          ((unsigned short*)Cv)[(size_t)(row0 + r) * N + col] = f2b(acc[fm][fn][r]);
        else
          ((float*)Cv)[(size_t)(row0 + r) * N + col] = acc[fm][fn][r];
      }
    }
  }
}

// ------------- RoPE + int8 quantize (qkv bf16); dequant scales TRANSPOSED [h][s] -------------
__global__ __launch_bounds__(256) void k_ropequant(const unsigned short* __restrict__ qkv,
                                                   const float* __restrict__ cost,
                                                   const float* __restrict__ sint,
                                                   unsigned short* __restrict__ q_int,
                                                   float* __restrict__ q_ds_t,
                                                   unsigned short* __restrict__ k_int,
                                                   float* __restrict__ k_ds_t,
                                                   unsigned short* __restrict__ v_bf) {
  int s = blockIdx.x;
  int wv = threadIdx.x >> 6, l = threadIdx.x & 63;
  int hh = blockIdx.y * 4 + wv;  // 0..47: [0,32) q, [32,40) k, [40,48) v
  const unsigned short* row = qkv + (size_t)s * NQKV;
  if (hh < NH + NKV) {
    int off = (hh < NH) ? hh * HD : DMODEL + (hh - NH) * HD;
    float t1 = b2f(row[off + l]), t2 = b2f(row[off + 64 + l]);
    float c1 = cost[s * HD + l],      sn1 = sint[s * HD + l];
    float c2 = cost[s * HD + 64 + l], sn2 = sint[s * HD + 64 + l];
    float o1 = t1 * c1 - t2 * sn1;
    float o2 = t2 * c2 + t1 * sn2;
    float amax = fmaxf(fabsf(o1), fabsf(o2));
#pragma unroll
    for (int m = 1; m < 64; m <<= 1) amax = fmaxf(amax, __shfl_xor(amax, m));
    amax = fmaxf(amax, 1e-5f);
    float scale = 127.0f / amax;
    float dscale = amax * (1.0f / 127.0f);
    float v1 = fminf(fmaxf(rintf(o1 * scale), -128.f), 127.f);
    float v2 = fminf(fmaxf(rintf(o2 * scale), -128.f), 127.f);
    if (hh < NH) {
      unsigned short* dst = q_int + ((size_t)s * NH + hh) * HD;
      dst[l] = f2b(v1); dst[l + 64] = f2b(v2);
      if (l == 0) q_ds_t[(size_t)hh * S_LEN + s] = dscale;
    } else {
      int kh = hh - NH;
      unsigned short* dst = k_int + ((size_t)s * NKV + kh) * HD;
      dst[l] = f2b(v1); dst[l + 64] = f2b(v2);
      if (l == 0) k_ds_t[(size_t)kh * S_LEN + s] = dscale;
    }
  } else {
    int vh = hh - (NH + NKV);
    const unsigned short* src = row + DMODEL + NKV * HD + vh * HD;
    unsigned short* dst = v_bf + ((size_t)s * NKV + vh) * HD;
    dst[l] = src[l];
    dst[l + 64] = src[l + 64];
  }
}

// ------------- causal GQA flash attention (round-8 proven): 2 heads/block, swapped QK^T -------------
__global__ __launch_bounds__(256) void k_attn(const unsigned short* __restrict__ q_int,
                                              const float* __restrict__ q_ds_t,
                                              const unsigned short* __restrict__ k_int,
                                              const float* __restrict__ k_ds_t,
                                              const unsigned short* __restrict__ v_t,
                                              unsigned short* __restrict__ o_bf) {
  __shared__ __align__(16) unsigned short K_lds[2][8192];
  __shared__ __align__(16) unsigned short V_lds[2][8192];
  __shared__ __align__(16) unsigned short P_lds[4][16 * 72];

  const int bid = blockIdx.x;
  const int kvh = bid & 7;                    // XCD-pinned K/V
  const int ha = kvh * 4 + ((bid >> 3) & 1) * 2;  // head pair base
  const int qt = 31 - (bid >> 4);             // LPT: longest first
  const int tid = threadIdx.x, wv = tid >> 6, l = tid & 63;
  const int l15 = l & 15, l4 = l >> 4;

  auto stage = [&](int b, int kt) {
    const unsigned short* kB = k_int + (size_t)kt * 64 * (NKV * HD) + kvh * HD;
    const unsigned short* vB = v_t + (size_t)kvh * HD * S_LEN + (size_t)kt * 64;
#pragma unroll
    for (int j = 0; j < 4; ++j) {
      int wi = j * 4 + wv;
      int slot = wi * 64 + l;
      int key = slot >> 4;
      int colb = ((slot & 15) * 16) ^ ((key & 7) << 4);
      gl16(kB + key * (NKV * HD) + (colb >> 1), &K_lds[b][wi * 512]);
      int d = slot >> 3;
      int ckb = ((slot & 7) * 16) ^ ((d & 7) << 4);
      gl16(vB + (size_t)d * S_LEN + (ckb >> 1), &V_lds[b][wi * 512]);
    }
  };

  const int qrow_lo = qt * 64 + wv * 16;
  const int qg = qrow_lo + l15;
  const int crow = qrow_lo + l4 * 4;

  bf16x8 qf[2][4];
  float qsS[2];
#pragma unroll
  for (int h2 = 0; h2 < 2; ++h2) {
    const unsigned short* qp = q_int + ((size_t)(qrow_lo + l15) * NH + ha + h2) * HD + l4 * 8;
#pragma unroll
    for (int kd = 0; kd < 4; ++kd) qf[h2][kd] = *(const bf16x8*)(qp + kd * 32);
    qsS[h2] = ATT_SCALE_L2E * q_ds_t[(size_t)(ha + h2) * S_LEN + qg];
  }

  float m_run[2] = {-3.0e38f, -3.0e38f};
  float l_run[2] = {0.f, 0.f};
  f32x4 o_acc[2][8] = {};

  const int nkt = qt + 1;
  stage(0, 0);
  __syncthreads();

  for (int kt = 0; kt < nkt; ++kt) {
    const int cur = kt & 1;
    f32x4 ksd[4];
    {
      const f32x4* kdp = (const f32x4*)(k_ds_t + (size_t)kvh * S_LEN + kt * 64 + l4 * 4);
#pragma unroll
      for (int nt = 0; nt < 4; ++nt) ksd[nt] = kdp[nt * 4];
    }
    if (kt + 1 < nkt) stage(cur ^ 1, kt + 1);

    f32x4 sacc[2][4] = {};
#pragma unroll
    for (int nt = 0; nt < 4; ++nt) {
      int key = nt * 16 + l15;
#pragma unroll
      for (int kd = 0; kd < 4; ++kd) {
        int byte = key * 256 + kd * 64 + l4 * 16;
        byte ^= (key & 7) << 4;
        bf16x8 kf = *(const bf16x8*)((const char*)&K_lds[cur][0] + byte);
        sacc[0][nt] = __builtin_amdgcn_mfma_f32_16x16x32_bf16(kf, qf[0][kd], sacc[0][nt], 0, 0, 0);
        sacc[1][nt] = __builtin_amdgcn_mfma_f32_16x16x32_bf16(kf, qf[1][kd], sacc[1][nt], 0, 0, 0);
      }
    }

    bf16x8 pa[2][2];
#pragma unroll
    for (int h2 = 0; h2 < 2; ++h2) {
      float p[4][4];
      float tmax = -3.0e38f;
#pragma unroll
      for (int nt = 0; nt < 4; ++nt) {
        int keyb = kt * 64 + nt * 16 + l4 * 4;
#pragma unroll
        for (int r = 0; r < 4; ++r) {
          float sc = sacc[h2][nt][r] * (qsS[h2] * ksd[nt][r]);
          sc = (keyb + r <= qg) ? sc : -3.0e38f;
          p[nt][r] = sc;
          tmax = fmaxf(tmax, sc);
        }
      }
      tmax = fmaxf(tmax, __shfl_xor(tmax, 16));
      tmax = fmaxf(tmax, __shfl_xor(tmax, 32));

      float nm = fmaxf(m_run[h2], tmax);
      bool need = tmax > m_run[h2] + 11.0f;
      if (__ballot(need)) {
        float corr = __builtin_amdgcn_exp2f(m_run[h2] - nm);
        m_run[h2] = nm;
        l_run[h2] *= corr;
        float cq[4];
#pragma unroll
        for (int r = 0; r < 4; ++r) cq[r] = __shfl(corr, (l & 48) | (l4 * 4 + r));
#pragma unroll
        for (int dt = 0; dt < 8; ++dt)
#pragma unroll
          for (int r = 0; r < 4; ++r) o_acc[h2][dt][r] *= cq[r];
      }

      float psum = 0.f;
#pragma unroll
      for (int nt = 0; nt < 4; ++nt)
#pragma unroll
        for (int r = 0; r < 4; ++r) {
          float e = __builtin_amdgcn_exp2f(p[nt][r] - m_run[h2]);
          p[nt][r] = e;
          psum += e;
        }
      psum += __shfl_xor(psum, 16);
      psum += __shfl_xor(psum, 32);
      l_run[h2] += psum;

#pragma unroll
      for (int nt = 0; nt < 4; ++nt) {
        bf16x4 pk;
        pk[0] = (__bf16)p[nt][0]; pk[1] = (__bf16)p[nt][1];
        pk[2] = (__bf16)p[nt][2]; pk[3] = (__bf16)p[nt][3];
        *(bf16x4*)((char*)&P_lds[wv][0] + l15 * 144 + nt * 32 + l4 * 8) = pk;
      }
#pragma unroll
      for (int kc = 0; kc < 2; ++kc)
        pa[h2][kc] = *(const bf16x8*)((const char*)&P_lds[wv][0] + l15 * 144 + kc * 64 + l4 * 16);
    }

#pragma unroll
    for (int dt = 0; dt < 8; ++dt) {
      int d = dt * 16 + l15;
      int swzv = (d & 7) << 4;
#pragma unroll
      for (int kc = 0; kc < 2; ++kc) {
        int byte = d * 128 + ((kc * 64 + l4 * 16) ^ swzv);
        bf16x8 vb = *(const bf16x8*)((const char*)&V_lds[cur][0] + byte);
        o_acc[0][dt] = __builtin_amdgcn_mfma_f32_16x16x32_bf16(pa[0][kc], vb, o_acc[0][dt], 0, 0, 0);
        o_acc[1][dt] = __builtin_amdgcn_mfma_f32_16x16x32_bf16(pa[1][kc], vb, o_acc[1][dt], 0, 0, 0);
      }
    }
    __syncthreads();
  }

#pragma unroll
  for (int h2 = 0; h2 < 2; ++h2) {
    float inv = 1.0f / l_run[h2];
    float invq[4];
#pragma unroll
    for (int r = 0; r < 4; ++r) invq[r] = __shfl(inv, (l & 48) | (l4 * 4 + r));
#pragma unroll
    for (int dt = 0; dt < 8; ++dt)
#pragma unroll
      for (int r = 0; r < 4; ++r)
        o_bf[(size_t)(crow + r) * (NH * HD) + (ha + h2) * HD + dt * 16 + l15] =
            f2b(o_acc[h2][dt][r] * invq[r]);
  }
}

extern "C" void kernel_launch(void* const* d_in, const int* in_sizes, int n_in,
                              void* d_out, int out_size, void* d_ws, size_t ws_size,
                              hipStream_t stream) {
  const float* x    = (const float*)d_in[0];
  const float* Wq   = (const float*)d_in[1];
  const float* Wk   = (const float*)d_in[2];
  const float* Wv   = (const float*)d_in[3];
  const float* Wo   = (const float*)d_in[4];
  const float* cost = (const float*)d_in[5];
  const float* sint = (const float*)d_in[6];
  float* out = (float*)d_out;
  char* ws = (char*)d_ws;

  unsigned short* xb     = (unsigned short*)(ws);                 // 16 MB (dead after gemm1)
  unsigned short* wqkv_t = (unsigned short*)(ws + 16777216);      // 48 MB (dead after gemm1)
  unsigned short* wo_t   = (unsigned short*)(ws + 67108864);      // 32 MB (4096x4096)
  unsigned short* qkv    = (unsigned short*)(ws + 100663296);     // 24 MB bf16 (dead after ropequant)
  unsigned short* q_int  = (unsigned short*)(ws + 150994944);     // 16 MB
  unsigned short* k_int  = (unsigned short*)(ws + 167772160);     // 4 MB
  unsigned short* v_bf   = (unsigned short*)(ws + 171966464);     // 4 MB
  float*          q_ds_t = (float*)(ws + 176160768);              // 256 KB [NH][S]
  float*          k_ds_t = (float*)(ws + 176422912);              // 64 KB  [NKV][S]
  unsigned short* o_bf   = (unsigned short*)(ws + 176488448);     // 16 MB
  unsigned short* v_t    = (unsigned short*)(ws);                 // 4 MB, aliases dead xb

  hipFuncSetAttribute((const void*)k_g128<3, true>,
                      hipFuncAttributeMaxDynamicSharedMemorySize, 81920);
  hipFuncSetAttribute((const void*)k_g128<2, false>,
                      hipFuncAttributeMaxDynamicSharedMemorySize, 65536);

  k_cvt_x<<<(S_LEN * DMODEL / 4) / 256, 256, 0, stream>>>(x, xb);
  k_transpose<<<dim3(64, 64), 256, 0, stream>>>(Wq, wqkv_t, 4096, 4096);
  k_transpose<<<dim3(64, 16), 256, 0, stream>>>(Wk, wqkv_t + (size_t)4096 * 4096, 4096, 1024);
  k_transpose<<<dim3(64, 16), 256, 0, stream>>>(Wv, wqkv_t + (size_t)5120 * 4096, 4096, 1024);
  k_transpose<<<dim3(64, 64), 256, 0, stream>>>(Wo, wo_t, 4096, 4096);
  // QKV proj: 128x192 tiles -> 16 x 32 = 512 blocks = exactly 2 blocks/CU; bf16 output
  k_g128<3, true><<<dim3(512), 512, 81920, stream>>>(xb, wqkv_t, qkv, 2048, 6144, 4096);
  k_ropequant<<<dim3(2048, 12), 256, 0, stream>>>(qkv, cost, sint, q_int, q_ds_t, k_int, k_ds_t, v_bf);
  k_vt<<<dim3(32, 2, 8), 256, 0, stream>>>(v_bf, v_t);
  // attention: 512 blocks (2 heads each, shared K/V), LPT order
  k_attn<<<dim3(512), 256, 0, stream>>>(q_int, q_ds_t, k_int, k_ds_t, v_t, o_bf);
  // out proj: 128x128 tiles -> 16 x 32 = 512 blocks = exactly 2 blocks/CU
  k_g128<2, false><<<dim3(512), 512, 65536, stream>>>(o_bf, wo_t, out, 2048, 4096, 4096);
}